// Round 2
// baseline (535.300 us; speedup 1.0000x reference)
//
#include <hip/hip_runtime.h>
#include <hip/hip_cooperative_groups.h>
#include <hip/hip_bf16.h>
#include <math.h>

namespace cg = cooperative_groups;

// N=10000, E=320000, in_dim=256, heads=4, hidden=64 (C1=256), out=40
#define IN_DIM 256
#define C1 256
#define H1 4
#define OUT_DIM 40
#define W2PAD 48
#define NEG_SLOPE 0.2f
#define DSTRIDE 128  // padded CSR stride; max degree ~58 << 128
#define GRID_NB 1024 // cooperative grid: 4 blocks/CU x 256 CU (VGPR<=128, LDS 33.8KB)

typedef __attribute__((ext_vector_type(8))) short bf16x8;
typedef __attribute__((ext_vector_type(4))) float f32x4;
typedef __attribute__((ext_vector_type(2))) float f32x2;

#define XS_LD 264  // LDS row stride (u16): 256 + 8 pad

__device__ __forceinline__ unsigned short f2bf(float f) {
    union { float f; unsigned u; } c; c.f = f;
    unsigned r = c.u + 0x7fffu + ((c.u >> 16) & 1u);
    return (unsigned short)(r >> 16);
}

__device__ __forceinline__ unsigned char f2fp8(float f) {
    return (unsigned char)__builtin_amdgcn_cvt_pk_fp8_f32(f, 0.f, 0, false);
}

__device__ __forceinline__ float sel4(float4 v, int h) {
    float r = v.x;
    r = (h == 1) ? v.y : r;
    r = (h == 2) ? v.z : r;
    r = (h == 3) ? v.w : r;
    return r;
}

__device__ __forceinline__ float leaky(float v) {
    return (v >= 0.0f) ? v : NEG_SLOPE * v;
}

// =====================================================================
// Fused cooperative kernel: prep -> (GEMM || scatter) -> node1 -> node2
// =====================================================================
__global__ void __launch_bounds__(256, 4) k_gat(
    const float* __restrict__ x, const int* __restrict__ ei,
    const float* __restrict__ W1, const float* __restrict__ a_src1,
    const float* __restrict__ a_dst1, const float* __restrict__ bias1,
    const float* __restrict__ W2, const float* __restrict__ a_src2,
    const float* __restrict__ a_dst2, const float* __restrict__ bias2,
    float* __restrict__ out,
    unsigned char* h1, unsigned short* W1t, unsigned short* W2t,
    unsigned short* h2b, float* as1, float* ad1, float* as2, float* ad2,
    float* w2s, float* w2d, int* fill, unsigned short* srcs,
    int N, int E, int ET, int G1) {
    cg::grid_group grid = cg::this_grid();
    __shared__ __align__(16) char smem[64 * XS_LD * 2];  // 33792 B, aliased per phase
    const int t = threadIdx.x;
    const int b = blockIdx.x;
    const int nb = GRID_NB;

    // ---------------- phase 0: prep (blocks 0..63, same as old k_prep) ----------------
    if (b < 64) {
        int g = b * 256 + t;
        if (g < N) fill[g << 4] = 0;
        if (g < C1) {
            float s = 0.0f, d = 0.0f;
#pragma unroll
            for (int j = 0; j < OUT_DIM; ++j) {
                float w = W2[g * OUT_DIM + j];
                s += w * a_src2[j];
                d += w * a_dst2[j];
            }
            w2s[g] = s;
            w2d[g] = d;
        }
        if (g < W2PAD * C1) {  // W2t[j][k] = W2[k][j], rows 40..47 zero
            int j = g >> 8, k = g & 255;
            W2t[g] = (j < OUT_DIM) ? f2bf(W2[k * OUT_DIM + j]) : 0;
        }
        // W1t: 64 blocks = 8x8 tiles of 32x32, transpose via LDS
        float (*s32)[33] = (float (*)[33])smem;
        int r0 = (b >> 3) * 32;   // k
        int c0 = (b & 7) * 32;    // col
        for (int i = t; i < 1024; i += 256) {
            int lr = i >> 5, lc = i & 31;
            s32[lr][lc] = W1[(r0 + lr) * 256 + c0 + lc];
        }
        __syncthreads();
        for (int i = t; i < 1024; i += 256) {
            int oc = i >> 5, ok = i & 31;
            W1t[(c0 + oc) * 256 + r0 + ok] = f2bf(s32[ok][oc]);
        }
    }
    grid.sync();

    // ---------------- phase 1: layer-1 MFMA GEMM (blocks < G1) || CSR scatter (rest) --------
    if (b >= G1) {
        int sb = b - G1, nsb = nb - G1;
        for (int e = sb * 256 + t; e < ET; e += nsb * 256) {
            int s, d;
            if (e < E) { s = ei[e]; d = ei[E + e]; }
            else       { s = e - E; d = s; }
            int pos = atomicAdd(&fill[d << 4], 1);
            srcs[(d << 7) + pos] = (unsigned short)s;
        }
    } else {
        unsigned short* xs = (unsigned short*)smem;
        int n0 = b * 64;
        for (int i = t; i < 4096; i += 256) {
            int r = i >> 6, c4 = i & 63;
            int n = n0 + r;
            float4 v = (n < N) ? ((const float4*)x)[(size_t)n * 64 + c4]
                               : make_float4(0.f, 0.f, 0.f, 0.f);
            uint2 pk;
            pk.x = (unsigned)f2bf(v.x) | ((unsigned)f2bf(v.y) << 16);
            pk.y = (unsigned)f2bf(v.z) | ((unsigned)f2bf(v.w) << 16);
            *((uint2*)&xs[r * XS_LD + c4 * 4]) = pk;
        }
        __syncthreads();

        int wv = t >> 6, lane = t & 63;
        int quad = lane >> 4, ln = lane & 15;

        f32x4 acc[4][4];
#pragma unroll
        for (int mt = 0; mt < 4; ++mt)
#pragma unroll
            for (int nt = 0; nt < 4; ++nt) acc[mt][nt] = (f32x4){0.f, 0.f, 0.f, 0.f};

#pragma unroll
        for (int kb = 0; kb < 8; ++kb) {
            bf16x8 af[4], bfv[4];
#pragma unroll
            for (int mt = 0; mt < 4; ++mt)
                af[mt] = *((bf16x8*)&xs[(mt * 16 + ln) * XS_LD + kb * 32 + quad * 8]);
#pragma unroll
            for (int nt = 0; nt < 4; ++nt)
                bfv[nt] = *((const bf16x8*)(W1t + ((wv * 64 + nt * 16 + ln) * 256 + kb * 32 + quad * 8)));
#pragma unroll
            for (int mt = 0; mt < 4; ++mt)
#pragma unroll
                for (int nt = 0; nt < 4; ++nt)
                    acc[mt][nt] = __builtin_amdgcn_mfma_f32_16x16x32_bf16(af[mt], bfv[nt], acc[mt][nt], 0, 0, 0);
        }

        // attention dots from registers
        float asv[4], adv[4];
#pragma unroll
        for (int nt = 0; nt < 4; ++nt) {
            int col = wv * 64 + nt * 16 + ln;
            asv[nt] = a_src1[col];
            adv[nt] = a_dst1[col];
        }
#pragma unroll
        for (int mt = 0; mt < 4; ++mt) {
            float ds[4] = {0.f, 0.f, 0.f, 0.f};
            float dd[4] = {0.f, 0.f, 0.f, 0.f};
#pragma unroll
            for (int nt = 0; nt < 4; ++nt) {
#pragma unroll
                for (int r = 0; r < 4; ++r) {
                    float v = acc[mt][nt][r];
                    ds[r] += v * asv[nt];
                    dd[r] += v * adv[nt];
                }
            }
#pragma unroll
            for (int r = 0; r < 4; ++r) {
                float vs = ds[r], vd = dd[r];
#pragma unroll
                for (int o = 1; o < 16; o <<= 1) {
                    vs += __shfl_xor(vs, o);
                    vd += __shfl_xor(vd, o);
                }
                if (ln == 0) {
                    int node = n0 + mt * 16 + quad * 4 + r;
                    if (node < N) {
                        as1[node * H1 + wv] = vs;
                        ad1[node * H1 + wv] = vd;
                    }
                }
            }
        }

        // h1 store: repack fp8 tile through LDS -> coalesced dwordx4 row stores
        __syncthreads();
        unsigned char* bt = (unsigned char*)xs;  // 64 x 256 byte tile
#pragma unroll
        for (int mt = 0; mt < 4; ++mt)
#pragma unroll
            for (int nt = 0; nt < 4; ++nt)
#pragma unroll
                for (int r = 0; r < 4; ++r)
                    bt[(mt * 16 + quad * 4 + r) * 256 + wv * 64 + nt * 16 + ln] = f2fp8(acc[mt][nt][r]);
        __syncthreads();
        const uint4* bt4 = (const uint4*)bt;
        uint4* h14 = (uint4*)(h1 + (size_t)n0 * C1);
        for (int i = t; i < 1024; i += 256) {
            int row = i >> 4;
            if (n0 + row < N) h14[i] = bt4[i];
        }
    }
    grid.sync();

    // ---------------- phase 2: node1 (softmax+aggregate + fused layer-2 GEMM) ----------------
    {
        const int w = t >> 6, lane = t & 63;
        const int half = lane >> 5, hl = lane & 31;
        const int h8 = hl >> 3;
        float4* esb = (float4*)smem;                            // es[4][64] = 4096 B
        unsigned short* Abuf = (unsigned short*)(smem + 4096);  // 16x256 bf16 = 8192 B
        const float* esw = (const float*)(esb + w * 64);
        const float4* as4 = (const float4*)as1;
        const int NG = (N + 3) >> 2;

        for (int ub = b; ub < NG; ub += nb) {
            int n = ub * 4 + w;
            bool valid = (n < N);
            int start = n << 7;
            int end = start + (valid ? fill[n << 4] : 0);
            float4 adn = valid ? ((const float4*)ad1)[n] : make_float4(0.f, 0.f, 0.f, 0.f);

            float4 S4 = make_float4(0.f, 0.f, 0.f, 0.f);
            float acc[8];
#pragma unroll
            for (int k = 0; k < 8; ++k) acc[k] = 0.f;

            for (int c = start; c < end; c += 64) {
                int cnt = min(64, end - c);
                int idx = c + lane;
                int sreg = (idx < end) ? (int)srcs[idx] : 0;
                float4 exv = make_float4(0.f, 0.f, 0.f, 0.f);
                if (idx < end) {
                    float4 a = as4[sreg];
                    exv.x = __expf(leaky(a.x + adn.x));
                    exv.y = __expf(leaky(a.y + adn.y));
                    exv.z = __expf(leaky(a.z + adn.z));
                    exv.w = __expf(leaky(a.w + adn.w));
                }
                S4.x += exv.x; S4.y += exv.y; S4.z += exv.z; S4.w += exv.w;
                esb[w * 64 + lane] = exv;

                int i = 0;
                // 8 edges per batch: each half-wave takes the even/odd edge of 4 pairs
                for (; i + 7 < cnt; i += 8) {
                    int s[4]; float a[4]; uint2 r[4];
#pragma unroll
                    for (int k = 0; k < 4; ++k) {
                        int j = i + 2 * k + half;
                        s[k] = __shfl(sreg, j);
                        a[k] = esw[j * 4 + h8];
                    }
#pragma unroll
                    for (int k = 0; k < 4; ++k)
                        r[k] = *((const uint2*)(h1 + (size_t)s[k] * C1) + hl);
#pragma unroll
                    for (int k = 0; k < 4; ++k) {
                        f32x2 lo0 = __builtin_amdgcn_cvt_pk_f32_fp8(r[k].x, false);
                        f32x2 hi0 = __builtin_amdgcn_cvt_pk_f32_fp8(r[k].x, true);
                        f32x2 lo1 = __builtin_amdgcn_cvt_pk_f32_fp8(r[k].y, false);
                        f32x2 hi1 = __builtin_amdgcn_cvt_pk_f32_fp8(r[k].y, true);
                        acc[0] += a[k] * lo0.x; acc[1] += a[k] * lo0.y;
                        acc[2] += a[k] * hi0.x; acc[3] += a[k] * hi0.y;
                        acc[4] += a[k] * lo1.x; acc[5] += a[k] * lo1.y;
                        acc[6] += a[k] * hi1.x; acc[7] += a[k] * hi1.y;
                    }
                }
                // tail: 2 edges per step
                for (; i < cnt; i += 2) {
                    int j = i + half;
                    int s0 = __shfl(sreg, j);
                    float a0 = esw[j * 4 + h8];
                    uint2 r0 = *((const uint2*)(h1 + (size_t)s0 * C1) + hl);
                    f32x2 lo0 = __builtin_amdgcn_cvt_pk_f32_fp8(r0.x, false);
                    f32x2 hi0 = __builtin_amdgcn_cvt_pk_f32_fp8(r0.x, true);
                    f32x2 lo1 = __builtin_amdgcn_cvt_pk_f32_fp8(r0.y, false);
                    f32x2 hi1 = __builtin_amdgcn_cvt_pk_f32_fp8(r0.y, true);
                    acc[0] += a0 * lo0.x; acc[1] += a0 * lo0.y;
                    acc[2] += a0 * hi0.x; acc[3] += a0 * hi0.y;
                    acc[4] += a0 * lo1.x; acc[5] += a0 * lo1.y;
                    acc[6] += a0 * hi1.x; acc[7] += a0 * hi1.y;
                }
            }

            // combine the two half-wave accumulators
#pragma unroll
            for (int k = 0; k < 8; ++k) acc[k] += __shfl_xor(acc[k], 32);

#pragma unroll
            for (int o = 32; o > 0; o >>= 1) {
                S4.x += __shfl_xor(S4.x, o);
                S4.y += __shfl_xor(S4.y, o);
                S4.z += __shfl_xor(S4.z, o);
                S4.w += __shfl_xor(S4.w, o);
            }
            float iS = 1.0f / sel4(S4, h8);
            float4 b0 = ((const float4*)bias1)[hl * 2];
            float4 b1 = ((const float4*)bias1)[hl * 2 + 1];
            float v0 = fmaxf(acc[0] * iS + b0.x, 0.f);
            float v1 = fmaxf(acc[1] * iS + b0.y, 0.f);
            float v2 = fmaxf(acc[2] * iS + b0.z, 0.f);
            float v3 = fmaxf(acc[3] * iS + b0.w, 0.f);
            float v4 = fmaxf(acc[4] * iS + b1.x, 0.f);
            float v5 = fmaxf(acc[5] * iS + b1.y, 0.f);
            float v6 = fmaxf(acc[6] * iS + b1.z, 0.f);
            float v7 = fmaxf(acc[7] * iS + b1.w, 0.f);
            if (half == 0) {
                uint4 pk;
                pk.x = (unsigned)f2bf(v0) | ((unsigned)f2bf(v1) << 16);
                pk.y = (unsigned)f2bf(v2) | ((unsigned)f2bf(v3) << 16);
                pk.z = (unsigned)f2bf(v4) | ((unsigned)f2bf(v5) << 16);
                pk.w = (unsigned)f2bf(v6) | ((unsigned)f2bf(v7) << 16);
                ((uint4*)&Abuf[w * 256])[hl] = pk;
            }

            float4 ws0 = ((const float4*)w2s)[hl * 2];
            float4 ws1 = ((const float4*)w2s)[hl * 2 + 1];
            float4 wd0 = ((const float4*)w2d)[hl * 2];
            float4 wd1 = ((const float4*)w2d)[hl * 2 + 1];
            float ps = v0 * ws0.x + v1 * ws0.y + v2 * ws0.z + v3 * ws0.w
                     + v4 * ws1.x + v5 * ws1.y + v6 * ws1.z + v7 * ws1.w;
            float pd = v0 * wd0.x + v1 * wd0.y + v2 * wd0.z + v3 * wd0.w
                     + v4 * wd1.x + v5 * wd1.y + v6 * wd1.z + v7 * wd1.w;
#pragma unroll
            for (int o = 16; o > 0; o >>= 1) {
                ps += __shfl_xor(ps, o);
                pd += __shfl_xor(pd, o);
            }
            if (lane == 0 && valid) { as2[n] = ps; ad2[n] = pd; }

            // fused layer-2 GEMM: 16x48x256 MFMA vs W2t; waves 0-2
            __syncthreads();
            if (w < 3) {
                int quad = lane >> 4, ln = lane & 15;
                f32x4 accm = (f32x4){0.f, 0.f, 0.f, 0.f};
                const unsigned short* bbase = W2t + (w * 16 + ln) * 256;
#pragma unroll
                for (int kb = 0; kb < 8; ++kb) {
                    bf16x8 af = *((bf16x8*)&Abuf[ln * 256 + kb * 32 + quad * 8]);
                    bf16x8 bfr = *((const bf16x8*)(bbase + kb * 32 + quad * 8));
                    accm = __builtin_amdgcn_mfma_f32_16x16x32_bf16(af, bfr, accm, 0, 0, 0);
                }
                int col = w * 16 + ln;
                if (col < OUT_DIM && quad == 0) {
#pragma unroll
                    for (int r = 0; r < 4; ++r) {
                        int node = ub * 4 + r;
                        if (node < N) h2b[(size_t)node * OUT_DIM + col] = f2bf(accm[r]);
                    }
                }
            }
            __syncthreads();  // protect Abuf/es reuse on next grid-stride iteration
        }
    }
    grid.sync();

    // ---------------- phase 3: node2 (layer-2 softmax+aggregate + log_softmax) ----------------
    {
        const int w = t >> 6, lane = t & 63;
        const int g = lane / 10;       // edge-group 0..5 active
        const int gl = lane - g * 10;  // owns channels gl*4..gl*4+3
        const int NG = (N + 3) >> 2;

        for (int ub = b; ub < NG; ub += nb) {
            int n = ub * 4 + w;
            if (n >= N) continue;
            int start = n << 7;
            int end = start + fill[n << 4];
            float adn = ad2[n];
            float S = 0.f;
            float acc0 = 0.f, acc1 = 0.f, acc2 = 0.f, acc3 = 0.f;

            for (int c = start; c < end; c += 64) {
                int cnt = min(64, end - c);
                int idx = c + lane;
                int sreg = (idx < end) ? (int)srcs[idx] : 0;
                float ex = (idx < end) ? __expf(leaky(as2[sreg] + adn)) : 0.f;
                S += ex;
                for (int i = 0; i < cnt; i += 12) {
                    int j0 = i + g, j1 = i + 6 + g;
                    int jc0 = min(j0, 63), jc1 = min(j1, 63);
                    int su0 = __shfl(sreg, jc0), su1 = __shfl(sreg, jc1);
                    float al0 = __shfl(ex, jc0), al1 = __shfl(ex, jc1);
                    if (j0 >= cnt) al0 = 0.f;
                    if (j1 >= cnt) al1 = 0.f;
                    uint2 r0 = *((const uint2*)(h2b + (size_t)su0 * OUT_DIM) + gl);
                    uint2 r1 = *((const uint2*)(h2b + (size_t)su1 * OUT_DIM) + gl);
                    acc0 += al0 * __uint_as_float(r0.x << 16)         + al1 * __uint_as_float(r1.x << 16);
                    acc1 += al0 * __uint_as_float(r0.x & 0xffff0000u) + al1 * __uint_as_float(r1.x & 0xffff0000u);
                    acc2 += al0 * __uint_as_float(r0.y << 16)         + al1 * __uint_as_float(r1.y << 16);
                    acc3 += al0 * __uint_as_float(r0.y & 0xffff0000u) + al1 * __uint_as_float(r1.y & 0xffff0000u);
                }
            }

            int l10 = min(lane + 10, 63), l20 = min(lane + 20, 63), l30 = min(lane + 30, 63);
            int l40 = min(lane + 40, 63), l50 = min(lane + 50, 63);
            float t0 = acc0 + __shfl(acc0, l10) + __shfl(acc0, l20) + __shfl(acc0, l30)
                            + __shfl(acc0, l40) + __shfl(acc0, l50);
            float t1 = acc1 + __shfl(acc1, l10) + __shfl(acc1, l20) + __shfl(acc1, l30)
                            + __shfl(acc1, l40) + __shfl(acc1, l50);
            float t2 = acc2 + __shfl(acc2, l10) + __shfl(acc2, l20) + __shfl(acc2, l30)
                            + __shfl(acc2, l40) + __shfl(acc2, l50);
            float t3 = acc3 + __shfl(acc3, l10) + __shfl(acc3, l20) + __shfl(acc3, l30)
                            + __shfl(acc3, l40) + __shfl(acc3, l50);
#pragma unroll
            for (int o = 32; o > 0; o >>= 1) S += __shfl_xor(S, o);

            bool act = lane < 10;
            float iS = 1.0f / S;
            float4 bz = make_float4(0.f, 0.f, 0.f, 0.f);
            if (act) bz = ((const float4*)bias2)[lane];
            float v0 = act ? (t0 * iS + bz.x) : -INFINITY;
            float v1 = act ? (t1 * iS + bz.y) : -INFINITY;
            float v2 = act ? (t2 * iS + bz.z) : -INFINITY;
            float v3 = act ? (t3 * iS + bz.w) : -INFINITY;
            float mx = fmaxf(fmaxf(v0, v1), fmaxf(v2, v3));
#pragma unroll
            for (int o = 8; o > 0; o >>= 1) mx = fmaxf(mx, __shfl_xor(mx, o));
            float e0 = act ? __expf(v0 - mx) : 0.f;
            float e1 = act ? __expf(v1 - mx) : 0.f;
            float e2 = act ? __expf(v2 - mx) : 0.f;
            float e3 = act ? __expf(v3 - mx) : 0.f;
            float esum = (e0 + e1) + (e2 + e3);
#pragma unroll
            for (int o = 8; o > 0; o >>= 1) esum += __shfl_xor(esum, o);
            if (act) {
                float l = mx + logf(esum);
                *((float4*)(out + (size_t)n * OUT_DIM) + lane) = make_float4(v0 - l, v1 - l, v2 - l, v3 - l);
            }
        }
    }
}

// =====================================================================
// Legacy 4-kernel path (fallback if cooperative launch is rejected)
// =====================================================================
__global__ void k_prep(int* __restrict__ fill, const float* __restrict__ W1,
                       unsigned short* __restrict__ W1t, const float* __restrict__ W2,
                       unsigned short* __restrict__ W2t, const float* __restrict__ a_src2,
                       const float* __restrict__ a_dst2, float* __restrict__ w2s,
                       float* __restrict__ w2d, int N) {
    int t = threadIdx.x;
    int g = blockIdx.x * 256 + t;
    if (g < N) fill[g << 4] = 0;
    if (g < C1) {
        float s = 0.0f, d = 0.0f;
#pragma unroll
        for (int j = 0; j < OUT_DIM; ++j) {
            float w = W2[g * OUT_DIM + j];
            s += w * a_src2[j];
            d += w * a_dst2[j];
        }
        w2s[g] = s;
        w2d[g] = d;
    }
    if (g < W2PAD * C1) {
        int j = g >> 8, k = g & 255;
        W2t[g] = (j < OUT_DIM) ? f2bf(W2[k * OUT_DIM + j]) : 0;
    }
    __shared__ float s32[32][33];
    int b = blockIdx.x;
    int r0 = (b >> 3) * 32;
    int c0 = (b & 7) * 32;
    for (int i = t; i < 1024; i += 256) {
        int lr = i >> 5, lc = i & 31;
        s32[lr][lc] = W1[(r0 + lr) * 256 + c0 + lc];
    }
    __syncthreads();
    for (int i = t; i < 1024; i += 256) {
        int oc = i >> 5, ok = i & 31;
        W1t[(c0 + oc) * 256 + r0 + ok] = f2bf(s32[ok][oc]);
    }
}

__global__ void __launch_bounds__(256) k_fused1(
    const float* __restrict__ x, const unsigned short* __restrict__ W1t,
    const float* __restrict__ a_src, const float* __restrict__ a_dst,
    unsigned char* __restrict__ h1, float* __restrict__ as1, float* __restrict__ ad1,
    const int* __restrict__ ei, int* __restrict__ fill, unsigned short* __restrict__ srcs,
    int N, int E, int ET, int G1) {
    __shared__ unsigned short xs[64 * XS_LD];
    int t = threadIdx.x;

    if (blockIdx.x >= G1) {
        int eb = (blockIdx.x - G1) * 1024 + t;
#pragma unroll
        for (int k = 0; k < 4; ++k) {
            int e = eb + k * 256;
            if (e < ET) {
                int s, d;
                if (e < E) { s = ei[e]; d = ei[E + e]; }
                else       { s = e - E; d = s; }
                int pos = atomicAdd(&fill[d << 4], 1);
                srcs[(d << 7) + pos] = (unsigned short)s;
            }
        }
        return;
    }

    int n0 = blockIdx.x * 64;
    for (int i = t; i < 4096; i += 256) {
        int r = i >> 6, c4 = i & 63;
        int n = n0 + r;
        float4 v = (n < N) ? ((const float4*)x)[(size_t)n * 64 + c4]
                           : make_float4(0.f, 0.f, 0.f, 0.f);
        uint2 pk;
        pk.x = (unsigned)f2bf(v.x) | ((unsigned)f2bf(v.y) << 16);
        pk.y = (unsigned)f2bf(v.z) | ((unsigned)f2bf(v.w) << 16);
        *((uint2*)&xs[r * XS_LD + c4 * 4]) = pk;
    }
    __syncthreads();

    int wv = t >> 6, lane = t & 63;
    int quad = lane >> 4, ln = lane & 15;

    f32x4 acc[4][4];
#pragma unroll
    for (int mt = 0; mt < 4; ++mt)
#pragma unroll
        for (int nt = 0; nt < 4; ++nt) acc[mt][nt] = (f32x4){0.f, 0.f, 0.f, 0.f};

#pragma unroll
    for (int kb = 0; kb < 8; ++kb) {
        bf16x8 af[4], bfv[4];
#pragma unroll
        for (int mt = 0; mt < 4; ++mt)
            af[mt] = *((bf16x8*)&xs[(mt * 16 + ln) * XS_LD + kb * 32 + quad * 8]);
#pragma unroll
        for (int nt = 0; nt < 4; ++nt)
            bfv[nt] = *((const bf16x8*)(W1t + ((wv * 64 + nt * 16 + ln) * 256 + kb * 32 + quad * 8)));
#pragma unroll
        for (int mt = 0; mt < 4; ++mt)
#pragma unroll
            for (int nt = 0; nt < 4; ++nt)
                acc[mt][nt] = __builtin_amdgcn_mfma_f32_16x16x32_bf16(af[mt], bfv[nt], acc[mt][nt], 0, 0, 0);
    }

    float asv[4], adv[4];
#pragma unroll
    for (int nt = 0; nt < 4; ++nt) {
        int col = wv * 64 + nt * 16 + ln;
        asv[nt] = a_src[col];
        adv[nt] = a_dst[col];
    }
#pragma unroll
    for (int mt = 0; mt < 4; ++mt) {
        float ds[4] = {0.f, 0.f, 0.f, 0.f};
        float dd[4] = {0.f, 0.f, 0.f, 0.f};
#pragma unroll
        for (int nt = 0; nt < 4; ++nt) {
#pragma unroll
            for (int r = 0; r < 4; ++r) {
                float v = acc[mt][nt][r];
                ds[r] += v * asv[nt];
                dd[r] += v * adv[nt];
            }
        }
#pragma unroll
        for (int r = 0; r < 4; ++r) {
            float vs = ds[r], vd = dd[r];
#pragma unroll
            for (int o = 1; o < 16; o <<= 1) {
                vs += __shfl_xor(vs, o);
                vd += __shfl_xor(vd, o);
            }
            if (ln == 0) {
                int node = n0 + mt * 16 + quad * 4 + r;
                if (node < N) {
                    as1[node * H1 + wv] = vs;
                    ad1[node * H1 + wv] = vd;
                }
            }
        }
    }

    __syncthreads();
    unsigned char* bt = (unsigned char*)xs;
#pragma unroll
    for (int mt = 0; mt < 4; ++mt)
#pragma unroll
        for (int nt = 0; nt < 4; ++nt)
#pragma unroll
            for (int r = 0; r < 4; ++r)
                bt[(mt * 16 + quad * 4 + r) * 256 + wv * 64 + nt * 16 + ln] = f2fp8(acc[mt][nt][r]);
    __syncthreads();
    const uint4* bt4 = (const uint4*)bt;
    uint4* h14 = (uint4*)(h1 + (size_t)n0 * C1);
    for (int i = t; i < 1024; i += 256) {
        int row = i >> 4;
        if (n0 + row < N) h14[i] = bt4[i];
    }
}

__global__ void __launch_bounds__(256) k_node1(
    const int* __restrict__ fill, const unsigned short* __restrict__ srcs,
    const float* __restrict__ as1f, const float* __restrict__ ad1f,
    const unsigned char* __restrict__ h1, const float* __restrict__ bias1,
    const float* __restrict__ w2s, const float* __restrict__ w2d,
    const unsigned short* __restrict__ W2t, unsigned short* __restrict__ h2b,
    float* __restrict__ as2, float* __restrict__ ad2, int N) {
    int w = threadIdx.x >> 6, lane = threadIdx.x & 63;
    int n = blockIdx.x * 4 + w;
    bool valid = (n < N);
    __shared__ float4 es[4][64];
    __shared__ unsigned short Abuf[16 * 256];
    int half = lane >> 5, hl = lane & 31;
    int h8 = hl >> 3;
    int start = n << 7;
    int end = start + (valid ? fill[n << 4] : 0);
    const float4* as4 = (const float4*)as1f;
    float4 adn = valid ? ((const float4*)ad1f)[n] : make_float4(0.f, 0.f, 0.f, 0.f);
    const float* esw = (const float*)&es[w][0];

    float4 S4 = make_float4(0.f, 0.f, 0.f, 0.f);
    float acc[8];
#pragma unroll
    for (int k = 0; k < 8; ++k) acc[k] = 0.f;

    for (int c = start; c < end; c += 64) {
        int cnt = min(64, end - c);
        int idx = c + lane;
        int sreg = (idx < end) ? (int)srcs[idx] : 0;
        float4 exv = make_float4(0.f, 0.f, 0.f, 0.f);
        if (idx < end) {
            float4 a = as4[sreg];
            exv.x = __expf(leaky(a.x + adn.x));
            exv.y = __expf(leaky(a.y + adn.y));
            exv.z = __expf(leaky(a.z + adn.z));
            exv.w = __expf(leaky(a.w + adn.w));
        }
        S4.x += exv.x; S4.y += exv.y; S4.z += exv.z; S4.w += exv.w;
        es[w][lane] = exv;

        int i = 0;
        for (; i + 7 < cnt; i += 8) {
            int s[4]; float a[4]; uint2 r[4];
#pragma unroll
            for (int k = 0; k < 4; ++k) {
                int j = i + 2 * k + half;
                s[k] = __shfl(sreg, j);
                a[k] = esw[j * 4 + h8];
            }
#pragma unroll
            for (int k = 0; k < 4; ++k)
                r[k] = *((const uint2*)(h1 + (size_t)s[k] * C1) + hl);
#pragma unroll
            for (int k = 0; k < 4; ++k) {
                f32x2 lo0 = __builtin_amdgcn_cvt_pk_f32_fp8(r[k].x, false);
                f32x2 hi0 = __builtin_amdgcn_cvt_pk_f32_fp8(r[k].x, true);
                f32x2 lo1 = __builtin_amdgcn_cvt_pk_f32_fp8(r[k].y, false);
                f32x2 hi1 = __builtin_amdgcn_cvt_pk_f32_fp8(r[k].y, true);
                acc[0] += a[k] * lo0.x; acc[1] += a[k] * lo0.y;
                acc[2] += a[k] * hi0.x; acc[3] += a[k] * hi0.y;
                acc[4] += a[k] * lo1.x; acc[5] += a[k] * lo1.y;
                acc[6] += a[k] * hi1.x; acc[7] += a[k] * hi1.y;
            }
        }
        for (; i < cnt; i += 2) {
            int j = i + half;
            int s0 = __shfl(sreg, j);
            float a0 = esw[j * 4 + h8];
            uint2 r0 = *((const uint2*)(h1 + (size_t)s0 * C1) + hl);
            f32x2 lo0 = __builtin_amdgcn_cvt_pk_f32_fp8(r0.x, false);
            f32x2 hi0 = __builtin_amdgcn_cvt_pk_f32_fp8(r0.x, true);
            f32x2 lo1 = __builtin_amdgcn_cvt_pk_f32_fp8(r0.y, false);
            f32x2 hi1 = __builtin_amdgcn_cvt_pk_f32_fp8(r0.y, true);
            acc[0] += a0 * lo0.x; acc[1] += a0 * lo0.y;
            acc[2] += a0 * hi0.x; acc[3] += a0 * hi0.y;
            acc[4] += a0 * lo1.x; acc[5] += a0 * lo1.y;
            acc[6] += a0 * hi1.x; acc[7] += a0 * hi1.y;
        }
    }

#pragma unroll
    for (int k = 0; k < 8; ++k) acc[k] += __shfl_xor(acc[k], 32);

#pragma unroll
    for (int o = 32; o > 0; o >>= 1) {
        S4.x += __shfl_xor(S4.x, o);
        S4.y += __shfl_xor(S4.y, o);
        S4.z += __shfl_xor(S4.z, o);
        S4.w += __shfl_xor(S4.w, o);
    }
    float iS = 1.0f / sel4(S4, h8);
    float4 b0 = ((const float4*)bias1)[hl * 2];
    float4 b1 = ((const float4*)bias1)[hl * 2 + 1];
    float v0 = fmaxf(acc[0] * iS + b0.x, 0.f);
    float v1 = fmaxf(acc[1] * iS + b0.y, 0.f);
    float v2 = fmaxf(acc[2] * iS + b0.z, 0.f);
    float v3 = fmaxf(acc[3] * iS + b0.w, 0.f);
    float v4 = fmaxf(acc[4] * iS + b1.x, 0.f);
    float v5 = fmaxf(acc[5] * iS + b1.y, 0.f);
    float v6 = fmaxf(acc[6] * iS + b1.z, 0.f);
    float v7 = fmaxf(acc[7] * iS + b1.w, 0.f);
    if (half == 0) {
        uint4 pk;
        pk.x = (unsigned)f2bf(v0) | ((unsigned)f2bf(v1) << 16);
        pk.y = (unsigned)f2bf(v2) | ((unsigned)f2bf(v3) << 16);
        pk.z = (unsigned)f2bf(v4) | ((unsigned)f2bf(v5) << 16);
        pk.w = (unsigned)f2bf(v6) | ((unsigned)f2bf(v7) << 16);
        ((uint4*)&Abuf[w * 256])[hl] = pk;
    }

    float4 ws0 = ((const float4*)w2s)[hl * 2];
    float4 ws1 = ((const float4*)w2s)[hl * 2 + 1];
    float4 wd0 = ((const float4*)w2d)[hl * 2];
    float4 wd1 = ((const float4*)w2d)[hl * 2 + 1];
    float ps = v0 * ws0.x + v1 * ws0.y + v2 * ws0.z + v3 * ws0.w
             + v4 * ws1.x + v5 * ws1.y + v6 * ws1.z + v7 * ws1.w;
    float pd = v0 * wd0.x + v1 * wd0.y + v2 * wd0.z + v3 * wd0.w
             + v4 * wd1.x + v5 * wd1.y + v6 * wd1.z + v7 * wd1.w;
#pragma unroll
    for (int o = 16; o > 0; o >>= 1) {
        ps += __shfl_xor(ps, o);
        pd += __shfl_xor(pd, o);
    }
    if (lane == 0 && valid) { as2[n] = ps; ad2[n] = pd; }

    __syncthreads();
    if (w < 3) {
        int quad = lane >> 4, ln = lane & 15;
        f32x4 accm = (f32x4){0.f, 0.f, 0.f, 0.f};
        const unsigned short* bbase = W2t + (w * 16 + ln) * 256;
#pragma unroll
        for (int kb = 0; kb < 8; ++kb) {
            bf16x8 af = *((bf16x8*)&Abuf[ln * 256 + kb * 32 + quad * 8]);
            bf16x8 bfr = *((const bf16x8*)(bbase + kb * 32 + quad * 8));
            accm = __builtin_amdgcn_mfma_f32_16x16x32_bf16(af, bfr, accm, 0, 0, 0);
        }
        int col = w * 16 + ln;
        if (col < OUT_DIM && quad == 0) {
#pragma unroll
            for (int r = 0; r < 4; ++r) {
                int node = blockIdx.x * 4 + r;
                if (node < N) h2b[(size_t)node * OUT_DIM + col] = f2bf(accm[r]);
            }
        }
    }
}

__global__ void __launch_bounds__(256) k_node2(
    const int* __restrict__ fill, const unsigned short* __restrict__ srcs,
    const float* __restrict__ as2, const float* __restrict__ ad2,
    const unsigned short* __restrict__ h2b, const float* __restrict__ bias2,
    float* __restrict__ out, int N) {
    int w = threadIdx.x >> 6, lane = threadIdx.x & 63;
    int n = blockIdx.x * 4 + w;
    if (n >= N) return;
    int g = lane / 10;
    int gl = lane - g * 10;
    int start = n << 7;
    int end = start + fill[n << 4];
    float adn = ad2[n];
    float S = 0.f;
    float acc0 = 0.f, acc1 = 0.f, acc2 = 0.f, acc3 = 0.f;

    for (int c = start; c < end; c += 64) {
        int cnt = min(64, end - c);
        int idx = c + lane;
        int sreg = (idx < end) ? (int)srcs[idx] : 0;
        float ex = (idx < end) ? __expf(leaky(as2[sreg] + adn)) : 0.f;
        S += ex;
        for (int i = 0; i < cnt; i += 12) {
            int j0 = i + g, j1 = i + 6 + g;
            int jc0 = min(j0, 63), jc1 = min(j1, 63);
            int su0 = __shfl(sreg, jc0), su1 = __shfl(sreg, jc1);
            float al0 = __shfl(ex, jc0), al1 = __shfl(ex, jc1);
            if (j0 >= cnt) al0 = 0.f;
            if (j1 >= cnt) al1 = 0.f;
            uint2 r0 = *((const uint2*)(h2b + (size_t)su0 * OUT_DIM) + gl);
            uint2 r1 = *((const uint2*)(h2b + (size_t)su1 * OUT_DIM) + gl);
            acc0 += al0 * __uint_as_float(r0.x << 16)         + al1 * __uint_as_float(r1.x << 16);
            acc1 += al0 * __uint_as_float(r0.x & 0xffff0000u) + al1 * __uint_as_float(r1.x & 0xffff0000u);
            acc2 += al0 * __uint_as_float(r0.y << 16)         + al1 * __uint_as_float(r1.y << 16);
            acc3 += al0 * __uint_as_float(r0.y & 0xffff0000u) + al1 * __uint_as_float(r1.y & 0xffff0000u);
        }
    }

    int l10 = min(lane + 10, 63), l20 = min(lane + 20, 63), l30 = min(lane + 30, 63);
    int l40 = min(lane + 40, 63), l50 = min(lane + 50, 63);
    float t0 = acc0 + __shfl(acc0, l10) + __shfl(acc0, l20) + __shfl(acc0, l30)
                    + __shfl(acc0, l40) + __shfl(acc0, l50);
    float t1 = acc1 + __shfl(acc1, l10) + __shfl(acc1, l20) + __shfl(acc1, l30)
                    + __shfl(acc1, l40) + __shfl(acc1, l50);
    float t2 = acc2 + __shfl(acc2, l10) + __shfl(acc2, l20) + __shfl(acc2, l30)
                    + __shfl(acc2, l40) + __shfl(acc2, l50);
    float t3 = acc3 + __shfl(acc3, l10) + __shfl(acc3, l20) + __shfl(acc3, l30)
                    + __shfl(acc3, l40) + __shfl(acc3, l50);
#pragma unroll
    for (int o = 32; o > 0; o >>= 1) S += __shfl_xor(S, o);

    bool act = lane < 10;
    float iS = 1.0f / S;
    float4 bz = make_float4(0.f, 0.f, 0.f, 0.f);
    if (act) bz = ((const float4*)bias2)[lane];
    float v0 = act ? (t0 * iS + bz.x) : -INFINITY;
    float v1 = act ? (t1 * iS + bz.y) : -INFINITY;
    float v2 = act ? (t2 * iS + bz.z) : -INFINITY;
    float v3 = act ? (t3 * iS + bz.w) : -INFINITY;
    float mx = fmaxf(fmaxf(v0, v1), fmaxf(v2, v3));
#pragma unroll
    for (int o = 8; o > 0; o >>= 1) mx = fmaxf(mx, __shfl_xor(mx, o));
    float e0 = act ? __expf(v0 - mx) : 0.f;
    float e1 = act ? __expf(v1 - mx) : 0.f;
    float e2 = act ? __expf(v2 - mx) : 0.f;
    float e3 = act ? __expf(v3 - mx) : 0.f;
    float esum = (e0 + e1) + (e2 + e3);
#pragma unroll
    for (int o = 8; o > 0; o >>= 1) esum += __shfl_xor(esum, o);
    if (act) {
        float l = mx + logf(esum);
        *((float4*)(out + (size_t)n * OUT_DIM) + lane) = make_float4(v0 - l, v1 - l, v2 - l, v3 - l);
    }
}

extern "C" void kernel_launch(void* const* d_in, const int* in_sizes, int n_in,
                              void* d_out, int out_size, void* d_ws, size_t ws_size,
                              hipStream_t stream) {
    const float* x        = (const float*)d_in[0];
    const int*   ei       = (const int*)d_in[1];
    const float* W1       = (const float*)d_in[2];
    const float* att_src1 = (const float*)d_in[3];
    const float* att_dst1 = (const float*)d_in[4];
    const float* bias1    = (const float*)d_in[5];
    const float* W2       = (const float*)d_in[6];
    const float* att_src2 = (const float*)d_in[7];
    const float* att_dst2 = (const float*)d_in[8];
    const float* bias2    = (const float*)d_in[9];
    float* out = (float*)d_out;

    const int N  = in_sizes[0] / IN_DIM;   // 10000
    const int E  = in_sizes[1] / 2;        // 320000
    const int ET = E + N;                  // 330000

    char* base = (char*)d_ws;
    auto alloc = [&](size_t bytes) {
        char* p = base;
        base += (bytes + 255) & ~(size_t)255;
        return p;
    };
    unsigned char*  h1    = (unsigned char*)alloc((size_t)N * C1);          // fp8
    unsigned short* W1t   = (unsigned short*)alloc((size_t)C1 * C1 * 2);
    unsigned short* W2t   = (unsigned short*)alloc((size_t)W2PAD * C1 * 2);
    unsigned short* h2b   = (unsigned short*)alloc((size_t)N * OUT_DIM * 2);  // bf16
    float* as1   = (float*)alloc((size_t)N * H1 * 4);
    float* ad1   = (float*)alloc((size_t)N * H1 * 4);
    float* as2   = (float*)alloc((size_t)N * 4);
    float* ad2   = (float*)alloc((size_t)N * 4);
    float* w2s   = (float*)alloc((size_t)C1 * 4);
    float* w2d   = (float*)alloc((size_t)C1 * 4);
    int* fill    = (int*)alloc((size_t)N * 16 * 4);  // 1 counter / 64B line
    unsigned short* srcs = (unsigned short*)alloc((size_t)N * DSTRIDE * 2);  // padded CSR, u16

    const int G1 = (N + 63) / 64;  // gemm blocks (157)

    int Ni = N, Ei = E, ETi = ET, G1i = G1;
    void* args[] = { (void*)&x, (void*)&ei, (void*)&W1, (void*)&att_src1, (void*)&att_dst1,
                     (void*)&bias1, (void*)&W2, (void*)&att_src2, (void*)&att_dst2,
                     (void*)&bias2, (void*)&out,
                     (void*)&h1, (void*)&W1t, (void*)&W2t, (void*)&h2b,
                     (void*)&as1, (void*)&ad1, (void*)&as2, (void*)&ad2,
                     (void*)&w2s, (void*)&w2d, (void*)&fill, (void*)&srcs,
                     (void*)&Ni, (void*)&Ei, (void*)&ETi, (void*)&G1i };

    hipError_t err = hipLaunchCooperativeKernel((void*)k_gat, dim3(GRID_NB), dim3(256),
                                                args, 0, stream);
    if (err != hipSuccess) {
        // fallback: proven 4-kernel pipeline
        const int GS = (ET + 1023) / 1024;
        k_prep<<<64, 256, 0, stream>>>(fill, W1, W1t, W2, W2t, att_src2, att_dst2, w2s, w2d, N);
        k_fused1<<<G1 + GS, 256, 0, stream>>>(x, W1t, att_src1, att_dst1, h1, as1, ad1,
                                              ei, fill, srcs, N, E, ET, G1);
        k_node1<<<(N + 3) / 4, 256, 0, stream>>>(fill, srcs, as1, ad1, h1, bias1, w2s, w2d,
                                                 W2t, h2b, as2, ad2, N);
        k_node2<<<(N + 3) / 4, 256, 0, stream>>>(fill, srcs, as2, ad2, h2b, bias2, out, N);
    }
}

// Round 3
// 139.659 us; speedup vs baseline: 3.8329x; 3.8329x over previous
//
#include <hip/hip_runtime.h>
#include <hip/hip_bf16.h>
#include <math.h>

// N=10000, E=320000, in_dim=256, heads=4, hidden=64 (C1=256), out=40
#define IN_DIM 256
#define C1 256
#define H1 4
#define OUT_DIM 40
#define W2PAD 48
#define NEG_SLOPE 0.2f
#define DSTRIDE 128  // padded CSR stride; max degree ~58 << 128
// fill: one counter per node, padded to its own 64B line (fill[n<<4])

typedef __attribute__((ext_vector_type(8))) short bf16x8;
typedef __attribute__((ext_vector_type(4))) float f32x4;
typedef __attribute__((ext_vector_type(2))) float f32x2;

#define XS_LD 264  // LDS row stride (u16): 256 + 8 pad

__device__ __forceinline__ unsigned short f2bf(float f) {
    union { float f; unsigned u; } c; c.f = f;
    unsigned r = c.u + 0x7fffu + ((c.u >> 16) & 1u);
    return (unsigned short)(r >> 16);
}

__device__ __forceinline__ unsigned char f2fp8(float f) {
    return (unsigned char)__builtin_amdgcn_cvt_pk_fp8_f32(f, 0.f, 0, false);
}

__device__ __forceinline__ float sel4(float4 v, int h) {
    float r = v.x;
    r = (h == 1) ? v.y : r;
    r = (h == 2) ? v.z : r;
    r = (h == 3) ? v.w : r;
    return r;
}

__device__ __forceinline__ float leaky(float v) {
    return (v >= 0.0f) ? v : NEG_SLOPE * v;
}

// ---------------- prep: fill=0 (padded), w2s/w2d, W1->W1t bf16, W2->W2t bf16 ----------------
__global__ void k_prep(int* __restrict__ fill, const float* __restrict__ W1,
                       unsigned short* __restrict__ W1t, const float* __restrict__ W2,
                       unsigned short* __restrict__ W2t, const float* __restrict__ a_src2,
                       const float* __restrict__ a_dst2, float* __restrict__ w2s,
                       float* __restrict__ w2d, int N) {
    int t = threadIdx.x;
    int g = blockIdx.x * 256 + t;
    if (g < N) fill[g << 4] = 0;
    if (g < C1) {
        float s = 0.0f, d = 0.0f;
#pragma unroll
        for (int j = 0; j < OUT_DIM; ++j) {
            float w = W2[g * OUT_DIM + j];
            s += w * a_src2[j];
            d += w * a_dst2[j];
        }
        w2s[g] = s;
        w2d[g] = d;
    }
    if (g < W2PAD * C1) {  // W2t[j][k] = W2[k][j], rows 40..47 zero
        int j = g >> 8, k = g & 255;
        W2t[g] = (j < OUT_DIM) ? f2bf(W2[k * OUT_DIM + j]) : 0;
    }
    // W1t: 64 blocks = 8x8 tiles of 32x32, transpose via LDS
    __shared__ float s32[32][33];
    int b = blockIdx.x;
    int r0 = (b >> 3) * 32;   // k
    int c0 = (b & 7) * 32;    // col
    for (int i = t; i < 1024; i += 256) {
        int lr = i >> 5, lc = i & 31;
        s32[lr][lc] = W1[(r0 + lr) * 256 + c0 + lc];
    }
    __syncthreads();
    for (int i = t; i < 1024; i += 256) {
        int oc = i >> 5, ok = i & 31;
        W1t[(c0 + oc) * 256 + r0 + ok] = f2bf(s32[ok][oc]);
    }
}

// ---------------- fused: layer-1 MFMA GEMM (blocks [0,G1)) + padded-CSR scatter (rest) ----------------
__global__ void __launch_bounds__(256) k_fused1(
    const float* __restrict__ x, const unsigned short* __restrict__ W1t,
    const float* __restrict__ a_src, const float* __restrict__ a_dst,
    unsigned char* __restrict__ h1, float* __restrict__ as1, float* __restrict__ ad1,
    const int* __restrict__ ei, int* __restrict__ fill, unsigned short* __restrict__ srcs,
    int N, int E, int ET, int G1) {
    __shared__ unsigned short xs[64 * XS_LD];
    int t = threadIdx.x;

    if (blockIdx.x >= G1) {
        int eb = (blockIdx.x - G1) * 1024 + t;
#pragma unroll
        for (int k = 0; k < 4; ++k) {
            int e = eb + k * 256;
            if (e < ET) {
                int s, d;
                if (e < E) { s = ei[e]; d = ei[E + e]; }
                else       { s = e - E; d = s; }
                int pos = atomicAdd(&fill[d << 4], 1);
                srcs[(d << 7) + pos] = (unsigned short)s;
            }
        }
        return;
    }

    int n0 = blockIdx.x * 64;
    for (int i = t; i < 4096; i += 256) {
        int r = i >> 6, c4 = i & 63;
        int n = n0 + r;
        float4 v = (n < N) ? ((const float4*)x)[(size_t)n * 64 + c4]
                           : make_float4(0.f, 0.f, 0.f, 0.f);
        uint2 pk;
        pk.x = (unsigned)f2bf(v.x) | ((unsigned)f2bf(v.y) << 16);
        pk.y = (unsigned)f2bf(v.z) | ((unsigned)f2bf(v.w) << 16);
        *((uint2*)&xs[r * XS_LD + c4 * 4]) = pk;
    }
    __syncthreads();

    int wv = t >> 6, lane = t & 63;
    int quad = lane >> 4, ln = lane & 15;

    f32x4 acc[4][4];
#pragma unroll
    for (int mt = 0; mt < 4; ++mt)
#pragma unroll
        for (int nt = 0; nt < 4; ++nt) acc[mt][nt] = (f32x4){0.f, 0.f, 0.f, 0.f};

#pragma unroll
    for (int kb = 0; kb < 8; ++kb) {
        bf16x8 af[4], bfv[4];
#pragma unroll
        for (int mt = 0; mt < 4; ++mt)
            af[mt] = *((bf16x8*)&xs[(mt * 16 + ln) * XS_LD + kb * 32 + quad * 8]);
#pragma unroll
        for (int nt = 0; nt < 4; ++nt)
            bfv[nt] = *((const bf16x8*)(W1t + ((wv * 64 + nt * 16 + ln) * 256 + kb * 32 + quad * 8)));
#pragma unroll
        for (int mt = 0; mt < 4; ++mt)
#pragma unroll
            for (int nt = 0; nt < 4; ++nt)
                acc[mt][nt] = __builtin_amdgcn_mfma_f32_16x16x32_bf16(af[mt], bfv[nt], acc[mt][nt], 0, 0, 0);
    }

    // attention dots from registers
    float asv[4], adv[4];
#pragma unroll
    for (int nt = 0; nt < 4; ++nt) {
        int col = wv * 64 + nt * 16 + ln;
        asv[nt] = a_src[col];
        adv[nt] = a_dst[col];
    }
#pragma unroll
    for (int mt = 0; mt < 4; ++mt) {
        float ds[4] = {0.f, 0.f, 0.f, 0.f};
        float dd[4] = {0.f, 0.f, 0.f, 0.f};
#pragma unroll
        for (int nt = 0; nt < 4; ++nt) {
#pragma unroll
            for (int r = 0; r < 4; ++r) {
                float v = acc[mt][nt][r];
                ds[r] += v * asv[nt];
                dd[r] += v * adv[nt];
            }
        }
#pragma unroll
        for (int r = 0; r < 4; ++r) {
            float vs = ds[r], vd = dd[r];
#pragma unroll
            for (int o = 1; o < 16; o <<= 1) {
                vs += __shfl_xor(vs, o);
                vd += __shfl_xor(vd, o);
            }
            if (ln == 0) {
                int node = n0 + mt * 16 + quad * 4 + r;
                if (node < N) {
                    as1[node * H1 + wv] = vs;
                    ad1[node * H1 + wv] = vd;
                }
            }
        }
    }

    // h1 store: repack fp8 tile through LDS -> coalesced dwordx4 row stores
    __syncthreads();
    unsigned char* bt = (unsigned char*)xs;  // 64 x 256 byte tile
#pragma unroll
    for (int mt = 0; mt < 4; ++mt)
#pragma unroll
        for (int nt = 0; nt < 4; ++nt)
#pragma unroll
            for (int r = 0; r < 4; ++r)
                bt[(mt * 16 + quad * 4 + r) * 256 + wv * 64 + nt * 16 + ln] = f2fp8(acc[mt][nt][r]);
    __syncthreads();
    const uint4* bt4 = (const uint4*)bt;
    uint4* h14 = (uint4*)(h1 + (size_t)n0 * C1);
    for (int i = t; i < 1024; i += 256) {
        int row = i >> 4;
        if (n0 + row < N) h14[i] = bt4[i];
    }
}

// ---------------- layer 1 node: wave-per-node softmax+aggregate, deep-pipelined gather
//                  (16-edge batches, 8 uint2 loads in flight), fused layer-2 GEMM ----------------
__global__ void __launch_bounds__(256) k_node1(
    const int* __restrict__ fill, const unsigned short* __restrict__ srcs,
    const float* __restrict__ as1f, const float* __restrict__ ad1f,
    const unsigned char* __restrict__ h1, const float* __restrict__ bias1,
    const float* __restrict__ w2s, const float* __restrict__ w2d,
    const unsigned short* __restrict__ W2t, unsigned short* __restrict__ h2b,
    float* __restrict__ as2, float* __restrict__ ad2, int N) {
    int w = threadIdx.x >> 6, lane = threadIdx.x & 63;
    int n = blockIdx.x * 4 + w;
    bool valid = (n < N);
    __shared__ float4 es[4][64];
    __shared__ unsigned short Abuf[16 * 256];  // 16 rows (4 valid) x 256 bf16
    int half = lane >> 5, hl = lane & 31;      // half-wave handles one edge; lane owns 8 channels
    int h8 = hl >> 3;                          // head of channels hl*8..hl*8+7 (8 | 64)
    int start = n << 7;
    int end = start + (valid ? fill[n << 4] : 0);
    const float4* as4 = (const float4*)as1f;
    float4 adn = valid ? ((const float4*)ad1f)[n] : make_float4(0.f, 0.f, 0.f, 0.f);
    const float* esw = (const float*)&es[w][0];

    float4 S4 = make_float4(0.f, 0.f, 0.f, 0.f);
    float acc[8];
#pragma unroll
    for (int k = 0; k < 8; ++k) acc[k] = 0.f;

    for (int c = start; c < end; c += 64) {
        int cnt = min(64, end - c);
        int idx = c + lane;
        int sreg = (idx < end) ? (int)srcs[idx] : 0;
        float4 exv = make_float4(0.f, 0.f, 0.f, 0.f);
        if (idx < end) {
            float4 a = as4[sreg];
            exv.x = __expf(leaky(a.x + adn.x));
            exv.y = __expf(leaky(a.y + adn.y));
            exv.z = __expf(leaky(a.z + adn.z));
            exv.w = __expf(leaky(a.w + adn.w));
        }
        S4.x += exv.x; S4.y += exv.y; S4.z += exv.z; S4.w += exv.w;
        es[w][lane] = exv;

        int i = 0;
        // 16 edges per batch: each half-wave takes the even/odd edge of 8 pairs;
        // 8 uint2 loads in flight per lane for latency hiding
        for (; i + 15 < cnt; i += 16) {
            int s[8]; float a[8]; uint2 r[8];
#pragma unroll
            for (int k = 0; k < 8; ++k) {
                int j = i + 2 * k + half;
                s[k] = __shfl(sreg, j);
                a[k] = esw[j * 4 + h8];
            }
#pragma unroll
            for (int k = 0; k < 8; ++k)
                r[k] = *((const uint2*)(h1 + (size_t)s[k] * C1) + hl);
#pragma unroll
            for (int k = 0; k < 8; ++k) {
                f32x2 lo0 = __builtin_amdgcn_cvt_pk_f32_fp8(r[k].x, false);
                f32x2 hi0 = __builtin_amdgcn_cvt_pk_f32_fp8(r[k].x, true);
                f32x2 lo1 = __builtin_amdgcn_cvt_pk_f32_fp8(r[k].y, false);
                f32x2 hi1 = __builtin_amdgcn_cvt_pk_f32_fp8(r[k].y, true);
                acc[0] += a[k] * lo0.x; acc[1] += a[k] * lo0.y;
                acc[2] += a[k] * hi0.x; acc[3] += a[k] * hi0.y;
                acc[4] += a[k] * lo1.x; acc[5] += a[k] * lo1.y;
                acc[6] += a[k] * hi1.x; acc[7] += a[k] * hi1.y;
            }
        }
        // 8-edge batch
        for (; i + 7 < cnt; i += 8) {
            int s[4]; float a[4]; uint2 r[4];
#pragma unroll
            for (int k = 0; k < 4; ++k) {
                int j = i + 2 * k + half;
                s[k] = __shfl(sreg, j);
                a[k] = esw[j * 4 + h8];
            }
#pragma unroll
            for (int k = 0; k < 4; ++k)
                r[k] = *((const uint2*)(h1 + (size_t)s[k] * C1) + hl);
#pragma unroll
            for (int k = 0; k < 4; ++k) {
                f32x2 lo0 = __builtin_amdgcn_cvt_pk_f32_fp8(r[k].x, false);
                f32x2 hi0 = __builtin_amdgcn_cvt_pk_f32_fp8(r[k].x, true);
                f32x2 lo1 = __builtin_amdgcn_cvt_pk_f32_fp8(r[k].y, false);
                f32x2 hi1 = __builtin_amdgcn_cvt_pk_f32_fp8(r[k].y, true);
                acc[0] += a[k] * lo0.x; acc[1] += a[k] * lo0.y;
                acc[2] += a[k] * hi0.x; acc[3] += a[k] * hi0.y;
                acc[4] += a[k] * lo1.x; acc[5] += a[k] * lo1.y;
                acc[6] += a[k] * hi1.x; acc[7] += a[k] * hi1.y;
            }
        }
        // tail: 2 edges per step; out-of-range edge gets alpha=0 naturally (ex padding)
        for (; i < cnt; i += 2) {
            int j = i + half;
            int s0 = __shfl(sreg, j);
            float a0 = esw[j * 4 + h8];
            uint2 r0 = *((const uint2*)(h1 + (size_t)s0 * C1) + hl);
            f32x2 lo0 = __builtin_amdgcn_cvt_pk_f32_fp8(r0.x, false);
            f32x2 hi0 = __builtin_amdgcn_cvt_pk_f32_fp8(r0.x, true);
            f32x2 lo1 = __builtin_amdgcn_cvt_pk_f32_fp8(r0.y, false);
            f32x2 hi1 = __builtin_amdgcn_cvt_pk_f32_fp8(r0.y, true);
            acc[0] += a0 * lo0.x; acc[1] += a0 * lo0.y;
            acc[2] += a0 * hi0.x; acc[3] += a0 * hi0.y;
            acc[4] += a0 * lo1.x; acc[5] += a0 * lo1.y;
            acc[6] += a0 * hi1.x; acc[7] += a0 * hi1.y;
        }
    }

    // combine the two half-wave accumulators (both halves end up with full sums)
#pragma unroll
    for (int k = 0; k < 8; ++k) acc[k] += __shfl_xor(acc[k], 32);

#pragma unroll
    for (int o = 32; o > 0; o >>= 1) {
        S4.x += __shfl_xor(S4.x, o);
        S4.y += __shfl_xor(S4.y, o);
        S4.z += __shfl_xor(S4.z, o);
        S4.w += __shfl_xor(S4.w, o);
    }
    float iS = 1.0f / sel4(S4, h8);
    float4 b0 = ((const float4*)bias1)[hl * 2];
    float4 b1 = ((const float4*)bias1)[hl * 2 + 1];
    float v0 = fmaxf(acc[0] * iS + b0.x, 0.f);
    float v1 = fmaxf(acc[1] * iS + b0.y, 0.f);
    float v2 = fmaxf(acc[2] * iS + b0.z, 0.f);
    float v3 = fmaxf(acc[3] * iS + b0.w, 0.f);
    float v4 = fmaxf(acc[4] * iS + b1.x, 0.f);
    float v5 = fmaxf(acc[5] * iS + b1.y, 0.f);
    float v6 = fmaxf(acc[6] * iS + b1.z, 0.f);
    float v7 = fmaxf(acc[7] * iS + b1.w, 0.f);
    if (half == 0) {  // halves hold identical values; one writes the A-tile row
        uint4 pk;
        pk.x = (unsigned)f2bf(v0) | ((unsigned)f2bf(v1) << 16);
        pk.y = (unsigned)f2bf(v2) | ((unsigned)f2bf(v3) << 16);
        pk.z = (unsigned)f2bf(v4) | ((unsigned)f2bf(v5) << 16);
        pk.w = (unsigned)f2bf(v6) | ((unsigned)f2bf(v7) << 16);
        ((uint4*)&Abuf[w * 256])[hl] = pk;
    }

    float4 ws0 = ((const float4*)w2s)[hl * 2];
    float4 ws1 = ((const float4*)w2s)[hl * 2 + 1];
    float4 wd0 = ((const float4*)w2d)[hl * 2];
    float4 wd1 = ((const float4*)w2d)[hl * 2 + 1];
    float ps = v0 * ws0.x + v1 * ws0.y + v2 * ws0.z + v3 * ws0.w
             + v4 * ws1.x + v5 * ws1.y + v6 * ws1.z + v7 * ws1.w;
    float pd = v0 * wd0.x + v1 * wd0.y + v2 * wd0.z + v3 * wd0.w
             + v4 * wd1.x + v5 * wd1.y + v6 * wd1.z + v7 * wd1.w;
    // reduce within each 32-half (each half spans all 256 channels)
#pragma unroll
    for (int o = 16; o > 0; o >>= 1) {
        ps += __shfl_xor(ps, o);
        pd += __shfl_xor(pd, o);
    }
    if (lane == 0 && valid) { as2[n] = ps; ad2[n] = pd; }

    // fused layer-2 GEMM: 16(rows, 4 valid) x 48 x 256 MFMA vs W2t; waves 0-2 take n-tiles
    __syncthreads();
    if (w < 3) {
        int quad = lane >> 4, ln = lane & 15;
        f32x4 accm = (f32x4){0.f, 0.f, 0.f, 0.f};
        const unsigned short* bbase = W2t + (w * 16 + ln) * 256;
#pragma unroll
        for (int kb = 0; kb < 8; ++kb) {
            bf16x8 af = *((bf16x8*)&Abuf[ln * 256 + kb * 32 + quad * 8]);
            bf16x8 bfr = *((const bf16x8*)(bbase + kb * 32 + quad * 8));
            accm = __builtin_amdgcn_mfma_f32_16x16x32_bf16(af, bfr, accm, 0, 0, 0);
        }
        int col = w * 16 + ln;
        if (col < OUT_DIM && quad == 0) {  // valid rows m=0..3 live in quad 0
#pragma unroll
            for (int r = 0; r < 4; ++r) {
                int node = blockIdx.x * 4 + r;
                if (node < N) h2b[(size_t)node * OUT_DIM + col] = f2bf(accm[r]);
            }
        }
    }
}

// ---------------- layer 2 node: wave-per-node, 24 edges/iter (10 lanes each, dwordx2,
//                  4 loads in flight), bf16 gather + log_softmax ----------------
__global__ void __launch_bounds__(256) k_node2(
    const int* __restrict__ fill, const unsigned short* __restrict__ srcs,
    const float* __restrict__ as2, const float* __restrict__ ad2,
    const unsigned short* __restrict__ h2b, const float* __restrict__ bias2,
    float* __restrict__ out, int N) {
    int w = threadIdx.x >> 6, lane = threadIdx.x & 63;
    int n = blockIdx.x * 4 + w;
    if (n >= N) return;
    int g = lane / 10;          // edge-group 0..5 active; lanes 60-63 (g=6) discarded
    int gl = lane - g * 10;     // lane-in-group: owns channels gl*4..gl*4+3
    int start = n << 7;
    int end = start + fill[n << 4];
    float adn = ad2[n];
    float S = 0.f;
    float acc0 = 0.f, acc1 = 0.f, acc2 = 0.f, acc3 = 0.f;

    for (int c = start; c < end; c += 64) {
        int cnt = min(64, end - c);
        int idx = c + lane;
        int sreg = (idx < end) ? (int)srcs[idx] : 0;
        float ex = (idx < end) ? __expf(leaky(as2[sreg] + adn)) : 0.f;
        S += ex;
        // 24 edges per iter: 4 steps x 6 groups, 8B loads, 4 in flight
        for (int i = 0; i < cnt; i += 24) {
            int j0 = i + g, j1 = i + 6 + g, j2 = i + 12 + g, j3 = i + 18 + g;
            int jc0 = min(j0, 63), jc1 = min(j1, 63), jc2 = min(j2, 63), jc3 = min(j3, 63);
            int su0 = __shfl(sreg, jc0), su1 = __shfl(sreg, jc1);
            int su2 = __shfl(sreg, jc2), su3 = __shfl(sreg, jc3);
            float al0 = __shfl(ex, jc0), al1 = __shfl(ex, jc1);
            float al2 = __shfl(ex, jc2), al3 = __shfl(ex, jc3);
            if (j0 >= cnt) al0 = 0.f;
            if (j1 >= cnt) al1 = 0.f;
            if (j2 >= cnt) al2 = 0.f;
            if (j3 >= cnt) al3 = 0.f;
            uint2 r0 = *((const uint2*)(h2b + (size_t)su0 * OUT_DIM) + gl);
            uint2 r1 = *((const uint2*)(h2b + (size_t)su1 * OUT_DIM) + gl);
            uint2 r2 = *((const uint2*)(h2b + (size_t)su2 * OUT_DIM) + gl);
            uint2 r3 = *((const uint2*)(h2b + (size_t)su3 * OUT_DIM) + gl);
            acc0 += al0 * __uint_as_float(r0.x << 16)         + al1 * __uint_as_float(r1.x << 16)
                  + al2 * __uint_as_float(r2.x << 16)         + al3 * __uint_as_float(r3.x << 16);
            acc1 += al0 * __uint_as_float(r0.x & 0xffff0000u) + al1 * __uint_as_float(r1.x & 0xffff0000u)
                  + al2 * __uint_as_float(r2.x & 0xffff0000u) + al3 * __uint_as_float(r3.x & 0xffff0000u);
            acc2 += al0 * __uint_as_float(r0.y << 16)         + al1 * __uint_as_float(r1.y << 16)
                  + al2 * __uint_as_float(r2.y << 16)         + al3 * __uint_as_float(r3.y << 16);
            acc3 += al0 * __uint_as_float(r0.y & 0xffff0000u) + al1 * __uint_as_float(r1.y & 0xffff0000u)
                  + al2 * __uint_as_float(r2.y & 0xffff0000u) + al3 * __uint_as_float(r3.y & 0xffff0000u);
        }
    }

    // gather the 6 group partials into lanes 0-9
    int l10 = min(lane + 10, 63), l20 = min(lane + 20, 63), l30 = min(lane + 30, 63);
    int l40 = min(lane + 40, 63), l50 = min(lane + 50, 63);
    float t0 = acc0 + __shfl(acc0, l10) + __shfl(acc0, l20) + __shfl(acc0, l30)
                    + __shfl(acc0, l40) + __shfl(acc0, l50);
    float t1 = acc1 + __shfl(acc1, l10) + __shfl(acc1, l20) + __shfl(acc1, l30)
                    + __shfl(acc1, l40) + __shfl(acc1, l50);
    float t2 = acc2 + __shfl(acc2, l10) + __shfl(acc2, l20) + __shfl(acc2, l30)
                    + __shfl(acc2, l40) + __shfl(acc2, l50);
    float t3 = acc3 + __shfl(acc3, l10) + __shfl(acc3, l20) + __shfl(acc3, l30)
                    + __shfl(acc3, l40) + __shfl(acc3, l50);
#pragma unroll
    for (int o = 32; o > 0; o >>= 1) S += __shfl_xor(S, o);

    bool act = lane < 10;
    float iS = 1.0f / S;
    float4 bz = make_float4(0.f, 0.f, 0.f, 0.f);
    if (act) bz = ((const float4*)bias2)[lane];
    float v0 = act ? (t0 * iS + bz.x) : -INFINITY;
    float v1 = act ? (t1 * iS + bz.y) : -INFINITY;
    float v2 = act ? (t2 * iS + bz.z) : -INFINITY;
    float v3 = act ? (t3 * iS + bz.w) : -INFINITY;
    float mx = fmaxf(fmaxf(v0, v1), fmaxf(v2, v3));
#pragma unroll
    for (int o = 8; o > 0; o >>= 1) mx = fmaxf(mx, __shfl_xor(mx, o));
    float e0 = act ? __expf(v0 - mx) : 0.f;
    float e1 = act ? __expf(v1 - mx) : 0.f;
    float e2 = act ? __expf(v2 - mx) : 0.f;
    float e3 = act ? __expf(v3 - mx) : 0.f;
    float esum = (e0 + e1) + (e2 + e3);
#pragma unroll
    for (int o = 8; o > 0; o >>= 1) esum += __shfl_xor(esum, o);
    if (act) {
        float l = mx + logf(esum);
        *((float4*)(out + (size_t)n * OUT_DIM) + lane) = make_float4(v0 - l, v1 - l, v2 - l, v3 - l);
    }
}

extern "C" void kernel_launch(void* const* d_in, const int* in_sizes, int n_in,
                              void* d_out, int out_size, void* d_ws, size_t ws_size,
                              hipStream_t stream) {
    const float* x        = (const float*)d_in[0];
    const int*   ei       = (const int*)d_in[1];
    const float* W1       = (const float*)d_in[2];
    const float* att_src1 = (const float*)d_in[3];
    const float* att_dst1 = (const float*)d_in[4];
    const float* bias1    = (const float*)d_in[5];
    const float* W2       = (const float*)d_in[6];
    const float* att_src2 = (const float*)d_in[7];
    const float* att_dst2 = (const float*)d_in[8];
    const float* bias2    = (const float*)d_in[9];
    float* out = (float*)d_out;

    const int N  = in_sizes[0] / IN_DIM;   // 10000
    const int E  = in_sizes[1] / 2;        // 320000
    const int ET = E + N;                  // 330000

    char* base = (char*)d_ws;
    auto alloc = [&](size_t bytes) {
        char* p = base;
        base += (bytes + 255) & ~(size_t)255;
        return p;
    };
    unsigned char*  h1    = (unsigned char*)alloc((size_t)N * C1);          // fp8
    unsigned short* W1t   = (unsigned short*)alloc((size_t)C1 * C1 * 2);
    unsigned short* W2t   = (unsigned short*)alloc((size_t)W2PAD * C1 * 2);
    unsigned short* h2b   = (unsigned short*)alloc((size_t)N * OUT_DIM * 2);  // bf16
    float* as1   = (float*)alloc((size_t)N * H1 * 4);
    float* ad1   = (float*)alloc((size_t)N * H1 * 4);
    float* as2   = (float*)alloc((size_t)N * 4);
    float* ad2   = (float*)alloc((size_t)N * 4);
    float* w2s   = (float*)alloc((size_t)C1 * 4);
    float* w2d   = (float*)alloc((size_t)C1 * 4);
    int* fill    = (int*)alloc((size_t)N * 16 * 4);  // 1 counter / 64B line
    unsigned short* srcs = (unsigned short*)alloc((size_t)N * DSTRIDE * 2);  // padded CSR, u16

    const int G1 = (N + 63) / 64;             // gemm blocks
    const int GS = (ET + 1023) / 1024;        // scatter blocks (4 edges/thread)

    k_prep<<<64, 256, 0, stream>>>(fill, W1, W1t, W2, W2t, att_src2, att_dst2, w2s, w2d, N);
    k_fused1<<<G1 + GS, 256, 0, stream>>>(x, W1t, att_src1, att_dst1, h1, as1, ad1,
                                          ei, fill, srcs, N, E, ET, G1);
    k_node1<<<(N + 3) / 4, 256, 0, stream>>>(fill, srcs, as1, ad1, h1, bias1, w2s, w2d,
                                             W2t, h2b, as2, ad2, N);
    k_node2<<<(N + 3) / 4, 256, 0, stream>>>(fill, srcs, as2, ad2, h2b, bias2, out, N);
}

// Round 7
// 135.058 us; speedup vs baseline: 3.9635x; 1.0341x over previous
//
#include <hip/hip_runtime.h>
#include <hip/hip_bf16.h>
#include <math.h>

// N=10000, E=320000, in_dim=256, heads=4, hidden=64 (C1=256), out=40
#define IN_DIM 256
#define C1 256
#define H1 4
#define OUT_DIM 40
#define W2PAD 48
#define NEG_SLOPE 0.2f
#define DSTRIDE 128  // padded CSR stride; max degree ~58 << 128
// fill: one counter per node, padded to its own 64B line (fill[n<<4])
//
// h1 channel permutation (layer-1 output, fp8): stored byte B of a row holds real
// channel c(B) = (B & 0xC0) + (B&3)*16 + ((B>>2)&15).  All per-channel tables
// (W2t rows, w2s/w2d, bias1p) are permuted identically in k_prep, so node1/node2
// consume it transparently.  Head index is preserved: c>>6 == B>>6.

typedef __attribute__((ext_vector_type(8))) short bf16x8;
typedef __attribute__((ext_vector_type(4))) float f32x4;
typedef __attribute__((ext_vector_type(2))) float f32x2;

#define XS_LD 264  // LDS row stride (u16): 256 + 8 pad
#define MT 2       // GEMM block rows = MT*16 = 32

__device__ __forceinline__ unsigned short f2bf(float f) {
    union { float f; unsigned u; } c; c.f = f;
    unsigned r = c.u + 0x7fffu + ((c.u >> 16) & 1u);
    return (unsigned short)(r >> 16);
}

__device__ __forceinline__ float sel4(float4 v, int h) {
    float r = v.x;
    r = (h == 1) ? v.y : r;
    r = (h == 2) ? v.z : r;
    r = (h == 3) ? v.w : r;
    return r;
}

__device__ __forceinline__ float leaky(float v) {
    return (v >= 0.0f) ? v : NEG_SLOPE * v;
}

__device__ __forceinline__ int permc(int B) {  // permuted byte index -> real channel
    return (B & 0xC0) + (B & 3) * 16 + ((B >> 2) & 15);
}

// ---------------- prep: fill=0, permuted tables (w2s/w2d/bias1p/W2t), W1->W1t bf16 ----------------
__global__ void k_prep(int* __restrict__ fill, const float* __restrict__ W1,
                       unsigned short* __restrict__ W1t, const float* __restrict__ W2,
                       unsigned short* __restrict__ W2t, const float* __restrict__ a_src2,
                       const float* __restrict__ a_dst2, float* __restrict__ w2s,
                       float* __restrict__ w2d, const float* __restrict__ bias1,
                       float* __restrict__ bias1p, int N) {
    int t = threadIdx.x;
    int g = blockIdx.x * 256 + t;
    if (g < N) fill[g << 4] = 0;
    if (g < C1) {  // g = permuted index B
        int c = permc(g);
        float s = 0.0f, d = 0.0f;
#pragma unroll
        for (int j = 0; j < OUT_DIM; ++j) {
            float w = W2[c * OUT_DIM + j];
            s += w * a_src2[j];
            d += w * a_dst2[j];
        }
        w2s[g] = s;
        w2d[g] = d;
        bias1p[g] = bias1[c];
    }
    if (g < W2PAD * C1) {  // W2t[j][B] = W2[c(B)][j], rows 40..47 zero
        int j = g >> 8, B = g & 255;
        W2t[g] = (j < OUT_DIM) ? f2bf(W2[permc(B) * OUT_DIM + j]) : 0;
    }
    // W1t: 64 blocks = 8x8 tiles of 32x32, transpose via LDS
    __shared__ float s32[32][33];
    int b = blockIdx.x;
    int r0 = (b >> 3) * 32;   // k
    int c0 = (b & 7) * 32;    // col
    for (int i = t; i < 1024; i += 256) {
        int lr = i >> 5, lc = i & 31;
        s32[lr][lc] = W1[(r0 + lr) * 256 + c0 + lc];
    }
    __syncthreads();
    for (int i = t; i < 1024; i += 256) {
        int oc = i >> 5, ok = i & 31;
        W1t[(c0 + oc) * 256 + r0 + ok] = f2bf(s32[ok][oc]);
    }
}

// ---------------- fused: layer-1 MFMA GEMM, 32-row tiles (blocks [0,G1)) + CSR scatter (rest) ----------------
__global__ void __launch_bounds__(256) k_fused1(
    const float* __restrict__ x, const unsigned short* __restrict__ W1t,
    const float* __restrict__ a_src, const float* __restrict__ a_dst,
    unsigned char* __restrict__ h1, float* __restrict__ as1, float* __restrict__ ad1,
    const int* __restrict__ ei, int* __restrict__ fill, unsigned short* __restrict__ srcs,
    int N, int E, int ET, int G1) {
    __shared__ unsigned short xs[32 * XS_LD];
    int t = threadIdx.x;

    if (blockIdx.x >= G1) {
        int eb = (blockIdx.x - G1) * 1024 + t;
#pragma unroll
        for (int k = 0; k < 4; ++k) {
            int e = eb + k * 256;
            if (e < ET) {
                int s, d;
                if (e < E) { s = ei[e]; d = ei[E + e]; }
                else       { s = e - E; d = s; }
                int pos = atomicAdd(&fill[d << 4], 1);
                srcs[(d << 7) + pos] = (unsigned short)s;
            }
        }
        return;
    }

    int n0 = blockIdx.x * (MT * 16);
    for (int i = t; i < 32 * 64; i += 256) {
        int r = i >> 6, c4 = i & 63;
        int n = n0 + r;
        float4 v = (n < N) ? ((const float4*)x)[(size_t)n * 64 + c4]
                           : make_float4(0.f, 0.f, 0.f, 0.f);
        uint2 pk;
        pk.x = (unsigned)f2bf(v.x) | ((unsigned)f2bf(v.y) << 16);
        pk.y = (unsigned)f2bf(v.z) | ((unsigned)f2bf(v.w) << 16);
        *((uint2*)&xs[r * XS_LD + c4 * 4]) = pk;
    }
    __syncthreads();

    int wv = t >> 6, lane = t & 63;
    int quad = lane >> 4, ln = lane & 15;

    f32x4 acc[MT][4];
#pragma unroll
    for (int mt = 0; mt < MT; ++mt)
#pragma unroll
        for (int nt = 0; nt < 4; ++nt) acc[mt][nt] = (f32x4){0.f, 0.f, 0.f, 0.f};

#pragma unroll
    for (int kb = 0; kb < 8; ++kb) {
        bf16x8 af[MT], bfv[4];
#pragma unroll
        for (int mt = 0; mt < MT; ++mt)
            af[mt] = *((bf16x8*)&xs[(mt * 16 + ln) * XS_LD + kb * 32 + quad * 8]);
#pragma unroll
        for (int nt = 0; nt < 4; ++nt)
            bfv[nt] = *((const bf16x8*)(W1t + ((wv * 64 + nt * 16 + ln) * 256 + kb * 32 + quad * 8)));
#pragma unroll
        for (int mt = 0; mt < MT; ++mt)
#pragma unroll
            for (int nt = 0; nt < 4; ++nt)
                acc[mt][nt] = __builtin_amdgcn_mfma_f32_16x16x32_bf16(af[mt], bfv[nt], acc[mt][nt], 0, 0, 0);
    }

    // attention dots from registers
    float asv[4], adv[4];
#pragma unroll
    for (int nt = 0; nt < 4; ++nt) {
        int col = wv * 64 + nt * 16 + ln;
        asv[nt] = a_src[col];
        adv[nt] = a_dst[col];
    }
#pragma unroll
    for (int mt = 0; mt < MT; ++mt) {
        float ds[4] = {0.f, 0.f, 0.f, 0.f};
        float dd[4] = {0.f, 0.f, 0.f, 0.f};
#pragma unroll
        for (int nt = 0; nt < 4; ++nt) {
#pragma unroll
            for (int r = 0; r < 4; ++r) {
                float v = acc[mt][nt][r];
                ds[r] += v * asv[nt];
                dd[r] += v * adv[nt];
            }
        }
#pragma unroll
        for (int r = 0; r < 4; ++r) {
            float vs = ds[r], vd = dd[r];
#pragma unroll
            for (int o = 1; o < 16; o <<= 1) {
                vs += __shfl_xor(vs, o);
                vd += __shfl_xor(vd, o);
            }
            if (ln == 0) {
                int node = n0 + mt * 16 + quad * 4 + r;
                if (node < N) {
                    as1[node * H1 + wv] = vs;
                    ad1[node * H1 + wv] = vd;
                }
            }
        }
    }

    // direct permuted fp8 store: byte B = wv*64 + ln*4 + nt of row <- acc[mt][nt][r]
    // (lane packs its 4 columns into one dword; quad writes a contiguous 64B segment)
#pragma unroll
    for (int mt = 0; mt < MT; ++mt) {
#pragma unroll
        for (int r = 0; r < 4; ++r) {
            int row = n0 + mt * 16 + quad * 4 + r;
            unsigned d = (unsigned)__builtin_amdgcn_cvt_pk_fp8_f32(acc[mt][0][r], acc[mt][1][r], 0, false);
            d = (unsigned)__builtin_amdgcn_cvt_pk_fp8_f32(acc[mt][2][r], acc[mt][3][r], d, true);
            if (row < N)
                *(unsigned*)(h1 + (size_t)row * C1 + wv * 64 + ln * 4) = d;
        }
    }
}

// ---------------- layer 1 node: wave-per-node softmax+aggregate (permuted channels),
//                  fused layer-2 GEMM (MFMA, permuted W2t) ----------------
__global__ void __launch_bounds__(256) k_node1(
    const int* __restrict__ fill, const unsigned short* __restrict__ srcs,
    const float* __restrict__ as1f, const float* __restrict__ ad1f,
    const unsigned char* __restrict__ h1, const float* __restrict__ bias1p,
    const float* __restrict__ w2s, const float* __restrict__ w2d,
    const unsigned short* __restrict__ W2t, unsigned short* __restrict__ h2b,
    float* __restrict__ as2, float* __restrict__ ad2, int N) {
    int w = threadIdx.x >> 6, lane = threadIdx.x & 63;
    int n = blockIdx.x * 4 + w;
    bool valid = (n < N);
    __shared__ float4 es[4][64];
    __shared__ unsigned short Abuf[16 * 256];  // 16 rows (4 valid) x 256 bf16 (permuted k)
    int half = lane >> 5, hl = lane & 31;      // half-wave handles one edge; lane owns 8 channels
    int h8 = hl >> 3;                          // head of bytes hl*8..hl*8+7 (permutation preserves head)
    int start = n << 7;
    int end = start + (valid ? fill[n << 4] : 0);
    const float4* as4 = (const float4*)as1f;
    float4 adn = valid ? ((const float4*)ad1f)[n] : make_float4(0.f, 0.f, 0.f, 0.f);
    const float* esw = (const float*)&es[w][0];

    float4 S4 = make_float4(0.f, 0.f, 0.f, 0.f);
    float acc[8];
#pragma unroll
    for (int k = 0; k < 8; ++k) acc[k] = 0.f;

    for (int c = start; c < end; c += 64) {
        int cnt = min(64, end - c);
        int idx = c + lane;
        int sreg = (idx < end) ? (int)srcs[idx] : 0;
        float4 exv = make_float4(0.f, 0.f, 0.f, 0.f);
        if (idx < end) {
            float4 a = as4[sreg];
            exv.x = __expf(leaky(a.x + adn.x));
            exv.y = __expf(leaky(a.y + adn.y));
            exv.z = __expf(leaky(a.z + adn.z));
            exv.w = __expf(leaky(a.w + adn.w));
        }
        S4.x += exv.x; S4.y += exv.y; S4.z += exv.z; S4.w += exv.w;
        es[w][lane] = exv;

        int i = 0;
        // 16 edges per batch: each half-wave takes the even/odd edge of 8 pairs;
        // 8 uint2 loads in flight per lane for latency hiding
        for (; i + 15 < cnt; i += 16) {
            int s[8]; float a[8]; uint2 r[8];
#pragma unroll
            for (int k = 0; k < 8; ++k) {
                int j = i + 2 * k + half;
                s[k] = __shfl(sreg, j);
                a[k] = esw[j * 4 + h8];
            }
#pragma unroll
            for (int k = 0; k < 8; ++k)
                r[k] = *((const uint2*)(h1 + (size_t)s[k] * C1) + hl);
#pragma unroll
            for (int k = 0; k < 8; ++k) {
                f32x2 lo0 = __builtin_amdgcn_cvt_pk_f32_fp8(r[k].x, false);
                f32x2 hi0 = __builtin_amdgcn_cvt_pk_f32_fp8(r[k].x, true);
                f32x2 lo1 = __builtin_amdgcn_cvt_pk_f32_fp8(r[k].y, false);
                f32x2 hi1 = __builtin_amdgcn_cvt_pk_f32_fp8(r[k].y, true);
                acc[0] += a[k] * lo0.x; acc[1] += a[k] * lo0.y;
                acc[2] += a[k] * hi0.x; acc[3] += a[k] * hi0.y;
                acc[4] += a[k] * lo1.x; acc[5] += a[k] * lo1.y;
                acc[6] += a[k] * hi1.x; acc[7] += a[k] * hi1.y;
            }
        }
        // 8-edge batch
        for (; i + 7 < cnt; i += 8) {
            int s[4]; float a[4]; uint2 r[4];
#pragma unroll
            for (int k = 0; k < 4; ++k) {
                int j = i + 2 * k + half;
                s[k] = __shfl(sreg, j);
                a[k] = esw[j * 4 + h8];
            }
#pragma unroll
            for (int k = 0; k < 4; ++k)
                r[k] = *((const uint2*)(h1 + (size_t)s[k] * C1) + hl);
#pragma unroll
            for (int k = 0; k < 4; ++k) {
                f32x2 lo0 = __builtin_amdgcn_cvt_pk_f32_fp8(r[k].x, false);
                f32x2 hi0 = __builtin_amdgcn_cvt_pk_f32_fp8(r[k].x, true);
                f32x2 lo1 = __builtin_amdgcn_cvt_pk_f32_fp8(r[k].y, false);
                f32x2 hi1 = __builtin_amdgcn_cvt_pk_f32_fp8(r[k].y, true);
                acc[0] += a[k] * lo0.x; acc[1] += a[k] * lo0.y;
                acc[2] += a[k] * hi0.x; acc[3] += a[k] * hi0.y;
                acc[4] += a[k] * lo1.x; acc[5] += a[k] * lo1.y;
                acc[6] += a[k] * hi1.x; acc[7] += a[k] * hi1.y;
            }
        }
        // tail: 2 edges per step; out-of-range edge gets alpha=0 naturally (ex padding)
        for (; i < cnt; i += 2) {
            int j = i + half;
            int s0 = __shfl(sreg, j);
            float a0 = esw[j * 4 + h8];
            uint2 r0 = *((const uint2*)(h1 + (size_t)s0 * C1) + hl);
            f32x2 lo0 = __builtin_amdgcn_cvt_pk_f32_fp8(r0.x, false);
            f32x2 hi0 = __builtin_amdgcn_cvt_pk_f32_fp8(r0.x, true);
            f32x2 lo1 = __builtin_amdgcn_cvt_pk_f32_fp8(r0.y, false);
            f32x2 hi1 = __builtin_amdgcn_cvt_pk_f32_fp8(r0.y, true);
            acc[0] += a0 * lo0.x; acc[1] += a0 * lo0.y;
            acc[2] += a0 * hi0.x; acc[3] += a0 * hi0.y;
            acc[4] += a0 * lo1.x; acc[5] += a0 * lo1.y;
            acc[6] += a0 * hi1.x; acc[7] += a0 * hi1.y;
        }
    }

    // combine the two half-wave accumulators (both halves end up with full sums)
#pragma unroll
    for (int k = 0; k < 8; ++k) acc[k] += __shfl_xor(acc[k], 32);

#pragma unroll
    for (int o = 32; o > 0; o >>= 1) {
        S4.x += __shfl_xor(S4.x, o);
        S4.y += __shfl_xor(S4.y, o);
        S4.z += __shfl_xor(S4.z, o);
        S4.w += __shfl_xor(S4.w, o);
    }
    float iS = 1.0f / sel4(S4, h8);
    float4 b0 = ((const float4*)bias1p)[hl * 2];
    float4 b1 = ((const float4*)bias1p)[hl * 2 + 1];
    float v0 = fmaxf(acc[0] * iS + b0.x, 0.f);
    float v1 = fmaxf(acc[1] * iS + b0.y, 0.f);
    float v2 = fmaxf(acc[2] * iS + b0.z, 0.f);
    float v3 = fmaxf(acc[3] * iS + b0.w, 0.f);
    float v4 = fmaxf(acc[4] * iS + b1.x, 0.f);
    float v5 = fmaxf(acc[5] * iS + b1.y, 0.f);
    float v6 = fmaxf(acc[6] * iS + b1.z, 0.f);
    float v7 = fmaxf(acc[7] * iS + b1.w, 0.f);
    if (half == 0) {  // halves hold identical values; one writes the A-tile row
        uint4 pk;
        pk.x = (unsigned)f2bf(v0) | ((unsigned)f2bf(v1) << 16);
        pk.y = (unsigned)f2bf(v2) | ((unsigned)f2bf(v3) << 16);
        pk.z = (unsigned)f2bf(v4) | ((unsigned)f2bf(v5) << 16);
        pk.w = (unsigned)f2bf(v6) | ((unsigned)f2bf(v7) << 16);
        ((uint4*)&Abuf[w * 256])[hl] = pk;
    }

    float4 ws0 = ((const float4*)w2s)[hl * 2];
    float4 ws1 = ((const float4*)w2s)[hl * 2 + 1];
    float4 wd0 = ((const float4*)w2d)[hl * 2];
    float4 wd1 = ((const float4*)w2d)[hl * 2 + 1];
    float ps = v0 * ws0.x + v1 * ws0.y + v2 * ws0.z + v3 * ws0.w
             + v4 * ws1.x + v5 * ws1.y + v6 * ws1.z + v7 * ws1.w;
    float pd = v0 * wd0.x + v1 * wd0.y + v2 * wd0.z + v3 * wd0.w
             + v4 * wd1.x + v5 * wd1.y + v6 * wd1.z + v7 * wd1.w;
    // reduce within each 32-half (each half spans all 256 channels)
#pragma unroll
    for (int o = 16; o > 0; o >>= 1) {
        ps += __shfl_xor(ps, o);
        pd += __shfl_xor(pd, o);
    }
    if (lane == 0 && valid) { as2[n] = ps; ad2[n] = pd; }

    // fused layer-2 GEMM: 16(rows, 4 valid) x 48 x 256 MFMA vs permuted W2t; waves 0-2
    __syncthreads();
    if (w < 3) {
        int quad = lane >> 4, ln = lane & 15;
        f32x4 accm = (f32x4){0.f, 0.f, 0.f, 0.f};
        const unsigned short* bbase = W2t + (w * 16 + ln) * 256;
#pragma unroll
        for (int kb = 0; kb < 8; ++kb) {
            bf16x8 af = *((bf16x8*)&Abuf[ln * 256 + kb * 32 + quad * 8]);
            bf16x8 bfr = *((const bf16x8*)(bbase + kb * 32 + quad * 8));
            accm = __builtin_amdgcn_mfma_f32_16x16x32_bf16(af, bfr, accm, 0, 0, 0);
        }
        int col = w * 16 + ln;
        if (col < OUT_DIM && quad == 0) {  // valid rows m=0..3 live in quad 0
#pragma unroll
            for (int r = 0; r < 4; ++r) {
                int node = blockIdx.x * 4 + r;
                if (node < N) h2b[(size_t)node * OUT_DIM + col] = f2bf(accm[r]);
            }
        }
    }
}

// ---------------- layer 2 node: wave-per-node, 24 edges/iter (10 lanes each, dwordx2,
//                  4 loads in flight), bf16 gather + log_softmax ----------------
__global__ void __launch_bounds__(256) k_node2(
    const int* __restrict__ fill, const unsigned short* __restrict__ srcs,
    const float* __restrict__ as2, const float* __restrict__ ad2,
    const unsigned short* __restrict__ h2b, const float* __restrict__ bias2,
    float* __restrict__ out, int N) {
    int w = threadIdx.x >> 6, lane = threadIdx.x & 63;
    int n = blockIdx.x * 4 + w;
    if (n >= N) return;
    int g = lane / 10;          // edge-group 0..5 active; lanes 60-63 (g=6) discarded
    int gl = lane - g * 10;     // lane-in-group: owns channels gl*4..gl*4+3
    int start = n << 7;
    int end = start + fill[n << 4];
    float adn = ad2[n];
    float S = 0.f;
    float acc0 = 0.f, acc1 = 0.f, acc2 = 0.f, acc3 = 0.f;

    for (int c = start; c < end; c += 64) {
        int cnt = min(64, end - c);
        int idx = c + lane;
        int sreg = (idx < end) ? (int)srcs[idx] : 0;
        float ex = (idx < end) ? __expf(leaky(as2[sreg] + adn)) : 0.f;
        S += ex;
        // 24 edges per iter: 4 steps x 6 groups, 8B loads, 4 in flight
        for (int i = 0; i < cnt; i += 24) {
            int j0 = i + g, j1 = i + 6 + g, j2 = i + 12 + g, j3 = i + 18 + g;
            int jc0 = min(j0, 63), jc1 = min(j1, 63), jc2 = min(j2, 63), jc3 = min(j3, 63);
            int su0 = __shfl(sreg, jc0), su1 = __shfl(sreg, jc1);
            int su2 = __shfl(sreg, jc2), su3 = __shfl(sreg, jc3);
            float al0 = __shfl(ex, jc0), al1 = __shfl(ex, jc1);
            float al2 = __shfl(ex, jc2), al3 = __shfl(ex, jc3);
            if (j0 >= cnt) al0 = 0.f;
            if (j1 >= cnt) al1 = 0.f;
            if (j2 >= cnt) al2 = 0.f;
            if (j3 >= cnt) al3 = 0.f;
            uint2 r0 = *((const uint2*)(h2b + (size_t)su0 * OUT_DIM) + gl);
            uint2 r1 = *((const uint2*)(h2b + (size_t)su1 * OUT_DIM) + gl);
            uint2 r2 = *((const uint2*)(h2b + (size_t)su2 * OUT_DIM) + gl);
            uint2 r3 = *((const uint2*)(h2b + (size_t)su3 * OUT_DIM) + gl);
            acc0 += al0 * __uint_as_float(r0.x << 16)         + al1 * __uint_as_float(r1.x << 16)
                  + al2 * __uint_as_float(r2.x << 16)         + al3 * __uint_as_float(r3.x << 16);
            acc1 += al0 * __uint_as_float(r0.x & 0xffff0000u) + al1 * __uint_as_float(r1.x & 0xffff0000u)
                  + al2 * __uint_as_float(r2.x & 0xffff0000u) + al3 * __uint_as_float(r3.x & 0xffff0000u);
            acc2 += al0 * __uint_as_float(r0.y << 16)         + al1 * __uint_as_float(r1.y << 16)
                  + al2 * __uint_as_float(r2.y << 16)         + al3 * __uint_as_float(r3.y << 16);
            acc3 += al0 * __uint_as_float(r0.y & 0xffff0000u) + al1 * __uint_as_float(r1.y & 0xffff0000u)
                  + al2 * __uint_as_float(r2.y & 0xffff0000u) + al3 * __uint_as_float(r3.y & 0xffff0000u);
        }
    }

    // gather the 6 group partials into lanes 0-9
    int l10 = min(lane + 10, 63), l20 = min(lane + 20, 63), l30 = min(lane + 30, 63);
    int l40 = min(lane + 40, 63), l50 = min(lane + 50, 63);
    float t0 = acc0 + __shfl(acc0, l10) + __shfl(acc0, l20) + __shfl(acc0, l30)
                    + __shfl(acc0, l40) + __shfl(acc0, l50);
    float t1 = acc1 + __shfl(acc1, l10) + __shfl(acc1, l20) + __shfl(acc1, l30)
                    + __shfl(acc1, l40) + __shfl(acc1, l50);
    float t2 = acc2 + __shfl(acc2, l10) + __shfl(acc2, l20) + __shfl(acc2, l30)
                    + __shfl(acc2, l40) + __shfl(acc2, l50);
    float t3 = acc3 + __shfl(acc3, l10) + __shfl(acc3, l20) + __shfl(acc3, l30)
                    + __shfl(acc3, l40) + __shfl(acc3, l50);
#pragma unroll
    for (int o = 32; o > 0; o >>= 1) S += __shfl_xor(S, o);

    bool act = lane < 10;
    float iS = 1.0f / S;
    float4 bz = make_float4(0.f, 0.f, 0.f, 0.f);
    if (act) bz = ((const float4*)bias2)[lane];
    float v0 = act ? (t0 * iS + bz.x) : -INFINITY;
    float v1 = act ? (t1 * iS + bz.y) : -INFINITY;
    float v2 = act ? (t2 * iS + bz.z) : -INFINITY;
    float v3 = act ? (t3 * iS + bz.w) : -INFINITY;
    float mx = fmaxf(fmaxf(v0, v1), fmaxf(v2, v3));
#pragma unroll
    for (int o = 8; o > 0; o >>= 1) mx = fmaxf(mx, __shfl_xor(mx, o));
    float e0 = act ? __expf(v0 - mx) : 0.f;
    float e1 = act ? __expf(v1 - mx) : 0.f;
    float e2 = act ? __expf(v2 - mx) : 0.f;
    float e3 = act ? __expf(v3 - mx) : 0.f;
    float esum = (e0 + e1) + (e2 + e3);
#pragma unroll
    for (int o = 8; o > 0; o >>= 1) esum += __shfl_xor(esum, o);
    if (act) {
        float l = mx + logf(esum);
        *((float4*)(out + (size_t)n * OUT_DIM) + lane) = make_float4(v0 - l, v1 - l, v2 - l, v3 - l);
    }
}

extern "C" void kernel_launch(void* const* d_in, const int* in_sizes, int n_in,
                              void* d_out, int out_size, void* d_ws, size_t ws_size,
                              hipStream_t stream) {
    const float* x        = (const float*)d_in[0];
    const int*   ei       = (const int*)d_in[1];
    const float* W1       = (const float*)d_in[2];
    const float* att_src1 = (const float*)d_in[3];
    const float* att_dst1 = (const float*)d_in[4];
    const float* bias1    = (const float*)d_in[5];
    const float* W2       = (const float*)d_in[6];
    const float* att_src2 = (const float*)d_in[7];
    const float* att_dst2 = (const float*)d_in[8];
    const float* bias2    = (const float*)d_in[9];
    float* out = (float*)d_out;

    const int N  = in_sizes[0] / IN_DIM;   // 10000
    const int E  = in_sizes[1] / 2;        // 320000
    const int ET = E + N;                  // 330000

    char* base = (char*)d_ws;
    auto alloc = [&](size_t bytes) {
        char* p = base;
        base += (bytes + 255) & ~(size_t)255;
        return p;
    };
    unsigned char*  h1    = (unsigned char*)alloc((size_t)N * C1);          // fp8, permuted channels
    unsigned short* W1t   = (unsigned short*)alloc((size_t)C1 * C1 * 2);
    unsigned short* W2t   = (unsigned short*)alloc((size_t)W2PAD * C1 * 2); // permuted k
    unsigned short* h2b   = (unsigned short*)alloc((size_t)N * OUT_DIM * 2);  // bf16
    float* as1    = (float*)alloc((size_t)N * H1 * 4);
    float* ad1    = (float*)alloc((size_t)N * H1 * 4);
    float* as2    = (float*)alloc((size_t)N * 4);
    float* ad2    = (float*)alloc((size_t)N * 4);
    float* w2s    = (float*)alloc((size_t)C1 * 4);   // permuted
    float* w2d    = (float*)alloc((size_t)C1 * 4);   // permuted
    float* bias1p = (float*)alloc((size_t)C1 * 4);   // permuted
    int* fill     = (int*)alloc((size_t)N * 16 * 4); // 1 counter / 64B line
    unsigned short* srcs = (unsigned short*)alloc((size_t)N * DSTRIDE * 2);  // padded CSR, u16

    const int G1 = (N + MT * 16 - 1) / (MT * 16);  // gemm blocks (313)
    const int GS = (ET + 1023) / 1024;             // scatter blocks (4 edges/thread)

    k_prep<<<64, 256, 0, stream>>>(fill, W1, W1t, W2, W2t, att_src2, att_dst2, w2s, w2d,
                                   bias1, bias1p, N);
    k_fused1<<<G1 + GS, 256, 0, stream>>>(x, W1t, att_src1, att_dst1, h1, as1, ad1,
                                          ei, fill, srcs, N, E, ET, G1);
    k_node1<<<(N + 3) / 4, 256, 0, stream>>>(fill, srcs, as1, ad1, h1, bias1p, w2s, w2d,
                                             W2t, h2b, as2, ad2, N);
    k_node2<<<(N + 3) / 4, 256, 0, stream>>>(fill, srcs, as2, ad2, h2b, bias2, out, N);
}